// Round 12
// baseline (254.616 us; speedup 1.0000x reference)
//
#include <hip/hip_runtime.h>
#include <hip/hip_bf16.h>
#include <hip/hip_fp8.h>

#define D_IN 128
#define D_H  256

typedef __attribute__((ext_vector_type(8))) short short8;   // 8 bf16 (4 VGPRs)
typedef __attribute__((ext_vector_type(4))) float floatx4;  // MFMA C/D frag

__device__ __forceinline__ unsigned short f2bf(float f) {
    __hip_bfloat16 h = __float2bfloat16(f);
    return *reinterpret_cast<unsigned short*>(&h);
}
__device__ __forceinline__ float bf2f(unsigned short s) {
    union { unsigned int u; float f; } v;
    v.u = ((unsigned int)s) << 16;
    return v.f;
}

// ------------- fused: histogram (+rank) AND fp32->bf16 conversions ---------
__global__ void hist_conv_k(const int* __restrict__ dst, int* __restrict__ deg,
                            int* __restrict__ rank, int E,
                            const float* __restrict__ x, unsigned short* __restrict__ xb, int nx4,
                            const float* __restrict__ w1l, unsigned short* __restrict__ w1lb,
                            const float* __restrict__ w1r, unsigned short* __restrict__ w1rb, int nw14,
                            const float* __restrict__ w2l, unsigned short* __restrict__ w2lb,
                            const float* __restrict__ w2r, unsigned short* __restrict__ w2rb, int nw24) {
    if (blockIdx.x < 512) {
        for (int e = blockIdx.x * 256 + threadIdx.x; e < E; e += 512 * 256)
            rank[e] = atomicAdd(&deg[dst[e]], 1);
        return;
    }
    int i = (blockIdx.x - 512) * 256 + threadIdx.x;
    const float* s; unsigned short* d; int k;
    if (i < nx4) { s = x; d = xb; k = i; }
    else {
        i -= nx4;
        if (i < nw14) { s = w1l; d = w1lb; k = i; }
        else {
            i -= nw14;
            if (i < nw14) { s = w1r; d = w1rb; k = i; }
            else {
                i -= nw14;
                if (i < nw24) { s = w2l; d = w2lb; k = i; }
                else {
                    i -= nw24;
                    if (i >= nw24) return;
                    s = w2r; d = w2rb; k = i;
                }
            }
        }
    }
    float4 v = ((const float4*)s)[k];
    ushort4 u;
    u.x = f2bf(v.x); u.y = f2bf(v.y); u.z = f2bf(v.z); u.w = f2bf(v.w);
    ((ushort4*)d)[k] = u;
}

__global__ __launch_bounds__(256) void scan_part_k(const int* __restrict__ deg,
                                                   int* __restrict__ bsum, int n) {
    const int b = blockIdx.x, tid = threadIdx.x;
    const int base = b * 2048;
    const int lim = min(base + 2048, n);
    int s = 0;
    for (int i = base + tid; i < lim; i += 256) s += deg[i];
    __shared__ int red[256];
    red[tid] = s; __syncthreads();
    for (int off = 128; off > 0; off >>= 1) {
        if (tid < off) red[tid] += red[tid + off];
        __syncthreads();
    }
    if (tid == 0) bsum[b] = red[0];
}

__global__ __launch_bounds__(256) void scan_final_k(const int* __restrict__ deg,
                                                    const int* __restrict__ bsum,
                                                    int* __restrict__ row_ptr,
                                                    int n, int E) {
    const int b = blockIdx.x, tid = threadIdx.x;
    const int base = b * 2048;
    __shared__ int buf[2048];
    __shared__ int ts[256];
    __shared__ int blk_prefix;
    if (tid == 0) {
        int p = 0;
        for (int i = 0; i < b; ++i) p += bsum[i];
        blk_prefix = p;
    }
    for (int i = tid; i < 2048; i += 256)
        buf[i] = (base + i < n) ? deg[base + i] : 0;
    __syncthreads();
    int local[8];
    int s = 0;
#pragma unroll
    for (int j = 0; j < 8; ++j) { local[j] = s; s += buf[tid * 8 + j]; }
    ts[tid] = s; __syncthreads();
    for (int off = 1; off < 256; off <<= 1) {
        int v = (tid >= off) ? ts[tid - off] : 0;
        __syncthreads();
        ts[tid] += v;
        __syncthreads();
    }
    const int prefix = blk_prefix + ((tid == 0) ? 0 : ts[tid - 1]);
#pragma unroll
    for (int j = 0; j < 8; ++j) {
        int idx = base + tid * 8 + j;
        if (idx < n) row_ptr[idx] = prefix + local[j];
    }
    if (b == 0 && tid == 0) row_ptr[n] = E;
}

__global__ void scatter_k(const int* __restrict__ src, const int* __restrict__ dst,
                          const int* __restrict__ rank, const int* __restrict__ row_ptr,
                          int* __restrict__ col, int E) {
    for (int e = blockIdx.x * blockDim.x + threadIdx.x; e < E; e += gridDim.x * blockDim.x)
        col[row_ptr[dst[e]] + rank[e]] = src[e];
}

// ---------------- agg layer 1: bf16 d=128, half-wave pair gather -----------
// col reads stay SCALAR (index j uniform); only the c0/c1 select is per-lane.
template <int UNP>  // neighbor-pairs per iteration
__device__ __forceinline__ int agg1_stage(const unsigned short* __restrict__ X,
                                          const int* __restrict__ col,
                                          int j, int e, int sel, int l32, float* acc) {
    for (; j + 2 * UNP <= e; j += 2 * UNP) {
        int c0[UNP], c1[UNP];
#pragma unroll
        for (int u = 0; u < UNP; ++u) { c0[u] = col[j + 2 * u]; c1[u] = col[j + 2 * u + 1]; }
        ushort4 vals[UNP];
#pragma unroll
        for (int u = 0; u < UNP; ++u) {
            const int cs = sel ? c1[u] : c0[u];
            vals[u] = *(const ushort4*)(X + (size_t)cs * 128 + l32 * 4);
        }
#pragma unroll
        for (int u = 0; u < UNP; ++u) {
            acc[0] += bf2f(vals[u].x); acc[1] += bf2f(vals[u].y);
            acc[2] += bf2f(vals[u].z); acc[3] += bf2f(vals[u].w);
        }
    }
    return j;
}

__global__ __launch_bounds__(256) void aggregate1_k(
    const unsigned short* __restrict__ X, const int* __restrict__ col,
    const int* __restrict__ rp, unsigned short* __restrict__ out, int Mnodes) {
    int node = __builtin_amdgcn_readfirstlane((blockIdx.x << 2) + (threadIdx.x >> 6));
    if (node >= Mnodes) return;
    const int lane = threadIdx.x & 63;
    const int sel = lane >> 5;
    const int l32 = lane & 31;
    const int s = rp[node], e = rp[node + 1];
    float acc[4] = {0.f, 0.f, 0.f, 0.f};

    int j = s;
    j = agg1_stage<4>(X, col, j, e, sel, l32, acc);   // 8 neighbors/iter
    j = agg1_stage<2>(X, col, j, e, sel, l32, acc);
    j = agg1_stage<1>(X, col, j, e, sel, l32, acc);
    if (j < e) {                                      // single leftover
        const int c0 = col[j];
        if (sel == 0) {
            const ushort4 v = *(const ushort4*)(X + (size_t)c0 * 128 + l32 * 4);
            acc[0] += bf2f(v.x); acc[1] += bf2f(v.y);
            acc[2] += bf2f(v.z); acc[3] += bf2f(v.w);
        }
    }
#pragma unroll
    for (int k = 0; k < 4; ++k) acc[k] += __shfl_xor(acc[k], 32, 64);
    const float inv = 1.f / fmaxf((float)(e - s), 1.f);
    if (sel == 0) {
        ushort4 o;
        o.x = f2bf(acc[0] * inv); o.y = f2bf(acc[1] * inv);
        o.z = f2bf(acc[2] * inv); o.w = f2bf(acc[3] * inv);
        *(ushort4*)(out + (size_t)node * 128 + l32 * 4) = o;
    }
}

// ---------------- agg layer 2: fp8 d=256, half-wave pair gather ------------
template <int UNP>
__device__ __forceinline__ int agg2_stage(const unsigned char* __restrict__ X8,
                                          const int* __restrict__ col,
                                          int j, int e, int sel, int l32, float* acc) {
    for (; j + 2 * UNP <= e; j += 2 * UNP) {
        int c0[UNP], c1[UNP];
#pragma unroll
        for (int u = 0; u < UNP; ++u) { c0[u] = col[j + 2 * u]; c1[u] = col[j + 2 * u + 1]; }
        uint2 vals[UNP];
#pragma unroll
        for (int u = 0; u < UNP; ++u) {
            const int cs = sel ? c1[u] : c0[u];
            vals[u] = *(const uint2*)(X8 + (size_t)cs * 256 + l32 * 8);
        }
#pragma unroll
        for (int u = 0; u < UNP; ++u) {
            __hip_fp8x4_e4m3 p0, p1;
            p0.__x = vals[u].x; p1.__x = vals[u].y;
            float4 f0 = (float4)p0, f1 = (float4)p1;
            acc[0] += f0.x; acc[1] += f0.y; acc[2] += f0.z; acc[3] += f0.w;
            acc[4] += f1.x; acc[5] += f1.y; acc[6] += f1.z; acc[7] += f1.w;
        }
    }
    return j;
}

__global__ __launch_bounds__(256) void aggregate2_k(
    const unsigned char* __restrict__ X8, const int* __restrict__ col,
    const int* __restrict__ rp, unsigned short* __restrict__ out, int Mnodes) {
    int node = __builtin_amdgcn_readfirstlane((blockIdx.x << 2) + (threadIdx.x >> 6));
    if (node >= Mnodes) return;
    const int lane = threadIdx.x & 63;
    const int sel = lane >> 5;
    const int l32 = lane & 31;
    const int s = rp[node], e = rp[node + 1];
    float acc[8] = {0.f, 0.f, 0.f, 0.f, 0.f, 0.f, 0.f, 0.f};

    int j = s;
    j = agg2_stage<4>(X8, col, j, e, sel, l32, acc);  // 8 neighbors/iter
    j = agg2_stage<2>(X8, col, j, e, sel, l32, acc);
    j = agg2_stage<1>(X8, col, j, e, sel, l32, acc);
    if (j < e) {
        const int c0 = col[j];
        if (sel == 0) {
            const uint2 v = *(const uint2*)(X8 + (size_t)c0 * 256 + l32 * 8);
            __hip_fp8x4_e4m3 p0, p1;
            p0.__x = v.x; p1.__x = v.y;
            float4 f0 = (float4)p0, f1 = (float4)p1;
            acc[0] += f0.x; acc[1] += f0.y; acc[2] += f0.z; acc[3] += f0.w;
            acc[4] += f1.x; acc[5] += f1.y; acc[6] += f1.z; acc[7] += f1.w;
        }
    }
#pragma unroll
    for (int k = 0; k < 8; ++k) acc[k] += __shfl_xor(acc[k], 32, 64);
    const float inv = 1.f / fmaxf((float)(e - s), 1.f);
    if (sel == 0) {
        unsigned short o[8];
#pragma unroll
        for (int k = 0; k < 8; ++k) o[k] = f2bf(acc[k] * inv);
        *(short8*)(out + (size_t)node * 256 + l32 * 8) = *(short8*)o;
    }
}

// ---------------- dual-input bf16 MFMA GEMM, block tile 128 x 256 ----------
template <int K, bool HEAD>
__global__ __launch_bounds__(256, 2) void gemm_mfma_k(
    const unsigned short* __restrict__ A1, const unsigned short* __restrict__ W1,
    const unsigned short* __restrict__ A2, const unsigned short* __restrict__ W2,
    const float* __restrict__ bias, unsigned short* __restrict__ Hout,
    unsigned char* __restrict__ Hout8,
    const float* __restrict__ hw, const float* __restrict__ hb,
    float* __restrict__ out, int M) {
    __shared__ __align__(16) unsigned short sA[128 * 40];
    __shared__ __align__(16) unsigned short sB[256 * 40];
    __shared__ float head_acc[128];

    const int tid = threadIdx.x;
    const int wave = tid >> 6;
    const int lane = tid & 63;
    const int c = lane & 15;
    const int q = lane >> 4;
    const int m0 = blockIdx.x * 128;

    if (HEAD && tid < 128) head_acc[tid] = 0.f;  // ordered by first k-loop barrier

    floatx4 acc[8][4];
#pragma unroll
    for (int mi = 0; mi < 8; ++mi)
#pragma unroll
        for (int ni = 0; ni < 4; ++ni) acc[mi][ni] = (floatx4){0.f, 0.f, 0.f, 0.f};

    const int arow = tid >> 1;          // 0..127
    const int aseg = (tid & 1) * 16;    // 0 or 16 (ushorts)
    const int brow = tid >> 2;          // 0..63
    const int bseg = (tid & 3) * 8;
    int gr = m0 + arow;
    if (gr >= M) gr = M - 1;            // clamp; stores guarded

    for (int phase = 0; phase < 2; ++phase) {
        const unsigned short* Ap = phase ? A2 : A1;
        const unsigned short* Wp = phase ? W2 : W1;
        for (int k0 = 0; k0 < K; k0 += 32) {
            short8 va0 = *(const short8*)(Ap + (size_t)gr * K + k0 + aseg);
            short8 va1 = *(const short8*)(Ap + (size_t)gr * K + k0 + aseg + 8);
            short8 vb[4];
#pragma unroll
            for (int i = 0; i < 4; ++i)
                vb[i] = *(const short8*)(Wp + (size_t)(brow + i * 64) * K + k0 + bseg);
            __syncthreads();
            *(short8*)&sA[arow * 40 + aseg] = va0;
            *(short8*)&sA[arow * 40 + aseg + 8] = va1;
#pragma unroll
            for (int i = 0; i < 4; ++i)
                *(short8*)&sB[(brow + i * 64) * 40 + bseg] = vb[i];
            __syncthreads();

            short8 af[8], bf[4];
#pragma unroll
            for (int mi = 0; mi < 8; ++mi)
                af[mi] = *(const short8*)&sA[(mi * 16 + c) * 40 + q * 8];
#pragma unroll
            for (int ni = 0; ni < 4; ++ni)
                bf[ni] = *(const short8*)&sB[(wave * 64 + ni * 16 + c) * 40 + q * 8];
#pragma unroll
            for (int mi = 0; mi < 8; ++mi)
#pragma unroll
                for (int ni = 0; ni < 4; ++ni)
                    acc[mi][ni] = __builtin_amdgcn_mfma_f32_16x16x32_bf16(
                        af[mi], bf[ni], acc[mi][ni], 0, 0, 0);
        }
    }

    if (!HEAD) {
#pragma unroll
        for (int mi = 0; mi < 8; ++mi)
#pragma unroll
            for (int ni = 0; ni < 4; ++ni) {
                const int n = wave * 64 + ni * 16 + c;
                const float bv = bias[n];
#pragma unroll
                for (int reg = 0; reg < 4; ++reg) {
                    const int m = m0 + mi * 16 + q * 4 + reg;
                    if (m < M) {
                        float v = fmaxf(acc[mi][ni][reg] + bv, 0.f);
                        Hout[(size_t)m * 256 + n] = f2bf(v);
                        __hip_fp8_e4m3 t(v);
                        Hout8[(size_t)m * 256 + n] = (unsigned char)t.__x;
                    }
                }
            }
    } else {
#pragma unroll
        for (int mi = 0; mi < 8; ++mi) {
            float p[4] = {0.f, 0.f, 0.f, 0.f};
#pragma unroll
            for (int ni = 0; ni < 4; ++ni) {
                const int n = wave * 64 + ni * 16 + c;
                const float bv = bias[n];
                const float hv = hw[n];
#pragma unroll
                for (int reg = 0; reg < 4; ++reg)
                    p[reg] += fmaxf(acc[mi][ni][reg] + bv, 0.f) * hv;
            }
#pragma unroll
            for (int reg = 0; reg < 4; ++reg) {
                float v = p[reg];
                v += __shfl_xor(v, 1, 64);
                v += __shfl_xor(v, 2, 64);
                v += __shfl_xor(v, 4, 64);
                v += __shfl_xor(v, 8, 64);
                if (c == 0) atomicAdd(&head_acc[mi * 16 + q * 4 + reg], v);
            }
        }
        __syncthreads();
        if (tid < 128) {
            const int m = m0 + tid;
            if (m < M) out[m] = head_acc[tid] + hb[0];
        }
    }
}

// ---------------- launch ----------------
extern "C" void kernel_launch(void* const* d_in, const int* in_sizes, int n_in,
                              void* d_out, int out_size, void* d_ws, size_t ws_size,
                              hipStream_t stream) {
    const float* x    = (const float*)d_in[0];
    const int*   ei   = (const int*)d_in[1];
    const float* W1l  = (const float*)d_in[2];
    const float* b1   = (const float*)d_in[3];
    const float* W1r  = (const float*)d_in[4];
    const float* W2l  = (const float*)d_in[5];
    const float* b2   = (const float*)d_in[6];
    const float* W2r  = (const float*)d_in[7];
    const float* hw   = (const float*)d_in[8];
    const float* hb   = (const float*)d_in[9];
    float* out = (float*)d_out;

    const int M = in_sizes[0] / D_IN;       // 50000
    const int E = in_sizes[1] / 2;          // 800000
    const int* src = ei;
    const int* dst = ei + E;

    size_t off = 0;
    auto alloc = [&](size_t bytes) -> void* {
        void* p = (char*)d_ws + off;
        off += (bytes + 255) & ~(size_t)255;
        return p;
    };
    int* deg  = (int*)alloc((size_t)M * 4);
    int* rp   = (int*)alloc((size_t)(M + 1) * 4);
    int* bsum = (int*)alloc(256 * 4);
    int* rank = (int*)alloc((size_t)E * 4);
    int* col  = (int*)alloc((size_t)E * 4);
    unsigned short* xb    = (unsigned short*)alloc((size_t)M * D_IN * 2);
    unsigned short* w1lb  = (unsigned short*)alloc((size_t)D_H * D_IN * 2);
    unsigned short* w1rb  = (unsigned short*)alloc((size_t)D_H * D_IN * 2);
    unsigned short* w2lb  = (unsigned short*)alloc((size_t)D_H * D_H * 2);
    unsigned short* w2rb  = (unsigned short*)alloc((size_t)D_H * D_H * 2);
    unsigned short* mean1 = (unsigned short*)alloc((size_t)M * D_IN * 2);
    unsigned short* h1    = (unsigned short*)alloc((size_t)M * D_H * 2);
    unsigned char*  h8    = (unsigned char*)alloc((size_t)M * D_H);
    unsigned short* mean2 = (unsigned short*)alloc((size_t)M * D_H * 2);

    hipMemsetAsync(deg, 0, (size_t)M * 4, stream);

    // fused histogram + conversions
    const int nx4 = (M * D_IN) / 4;
    const int nw14 = (D_H * D_IN) / 4;
    const int nw24 = (D_H * D_H) / 4;
    const int tot4 = nx4 + 2 * nw14 + 2 * nw24;
    const int convblk = (tot4 + 255) / 256;
    hist_conv_k<<<512 + convblk, 256, 0, stream>>>(
        dst, deg, rank, E,
        x, xb, nx4, W1l, w1lb, W1r, w1rb, nw14, W2l, w2lb, W2r, w2rb, nw24);

    // scan + scatter
    const int nseg = (M + 2047) / 2048;     // 25
    scan_part_k<<<nseg, 256, 0, stream>>>(deg, bsum, M);
    scan_final_k<<<nseg, 256, 0, stream>>>(deg, bsum, rp, M, E);
    scatter_k<<<512, 256, 0, stream>>>(src, dst, rank, rp, col, E);

    const int nblk = (M + 127) / 128;
    const int ablk = (M + 3) / 4;

    // layer 1
    aggregate1_k<<<ablk, 256, 0, stream>>>(xb, col, rp, mean1, M);
    gemm_mfma_k<D_IN, false><<<nblk, 256, 0, stream>>>(
        mean1, w1lb, xb, w1rb, b1, h1, h8, nullptr, nullptr, nullptr, M);

    // layer 2 + fused head (gather from fp8 h8; self path stays bf16 h1)
    aggregate2_k<<<ablk, 256, 0, stream>>>(h8, col, rp, mean2, M);
    gemm_mfma_k<D_H, true><<<nblk, 256, 0, stream>>>(
        mean2, w2lb, h1, w2rb, b2, nullptr, nullptr, hw, hb, out, M);
}

// Round 13
// 247.934 us; speedup vs baseline: 1.0269x; 1.0269x over previous
//
#include <hip/hip_runtime.h>
#include <hip/hip_bf16.h>
#include <hip/hip_fp8.h>

#define D_IN 128
#define D_H  256

typedef __attribute__((ext_vector_type(8))) short short8;   // 8 bf16 (4 VGPRs)
typedef __attribute__((ext_vector_type(4))) float floatx4;  // MFMA C/D frag

__device__ __forceinline__ unsigned short f2bf(float f) {
    __hip_bfloat16 h = __float2bfloat16(f);
    return *reinterpret_cast<unsigned short*>(&h);
}
__device__ __forceinline__ float bf2f(unsigned short s) {
    union { unsigned int u; float f; } v;
    v.u = ((unsigned int)s) << 16;
    return v.f;
}
__device__ __forceinline__ unsigned char f2fp8(float f) {
    __hip_fp8_e4m3 t(f);
    return (unsigned char)t.__x;
}

// ------------- fused: histogram (+rank) AND fp32->bf16/fp8 conversions -----
// x additionally gets an fp8 shadow copy (gather source for layer 1).
__global__ void hist_conv_k(const int* __restrict__ dst, int* __restrict__ deg,
                            int* __restrict__ rank, int E,
                            const float* __restrict__ x, unsigned short* __restrict__ xb,
                            unsigned char* __restrict__ xb8, int nx4,
                            const float* __restrict__ w1l, unsigned short* __restrict__ w1lb,
                            const float* __restrict__ w1r, unsigned short* __restrict__ w1rb, int nw14,
                            const float* __restrict__ w2l, unsigned short* __restrict__ w2lb,
                            const float* __restrict__ w2r, unsigned short* __restrict__ w2rb, int nw24) {
    if (blockIdx.x < 512) {
        for (int e = blockIdx.x * 256 + threadIdx.x; e < E; e += 512 * 256)
            rank[e] = atomicAdd(&deg[dst[e]], 1);
        return;
    }
    int i = (blockIdx.x - 512) * 256 + threadIdx.x;
    if (i < nx4) {
        float4 v = ((const float4*)x)[i];
        ushort4 u;
        u.x = f2bf(v.x); u.y = f2bf(v.y); u.z = f2bf(v.z); u.w = f2bf(v.w);
        ((ushort4*)xb)[i] = u;
        uchar4 c;
        c.x = f2fp8(v.x); c.y = f2fp8(v.y); c.z = f2fp8(v.z); c.w = f2fp8(v.w);
        ((uchar4*)xb8)[i] = c;
        return;
    }
    i -= nx4;
    const float* s; unsigned short* d; int k;
    if (i < nw14) { s = w1l; d = w1lb; k = i; }
    else {
        i -= nw14;
        if (i < nw14) { s = w1r; d = w1rb; k = i; }
        else {
            i -= nw14;
            if (i < nw24) { s = w2l; d = w2lb; k = i; }
            else {
                i -= nw24;
                if (i >= nw24) return;
                s = w2r; d = w2rb; k = i;
            }
        }
    }
    float4 v = ((const float4*)s)[k];
    ushort4 u;
    u.x = f2bf(v.x); u.y = f2bf(v.y); u.z = f2bf(v.z); u.w = f2bf(v.w);
    ((ushort4*)d)[k] = u;
}

__global__ __launch_bounds__(256) void scan_part_k(const int* __restrict__ deg,
                                                   int* __restrict__ bsum, int n) {
    const int b = blockIdx.x, tid = threadIdx.x;
    const int base = b * 2048;
    const int lim = min(base + 2048, n);
    int s = 0;
    for (int i = base + tid; i < lim; i += 256) s += deg[i];
    __shared__ int red[256];
    red[tid] = s; __syncthreads();
    for (int off = 128; off > 0; off >>= 1) {
        if (tid < off) red[tid] += red[tid + off];
        __syncthreads();
    }
    if (tid == 0) bsum[b] = red[0];
}

__global__ __launch_bounds__(256) void scan_final_k(const int* __restrict__ deg,
                                                    const int* __restrict__ bsum,
                                                    int* __restrict__ row_ptr,
                                                    int n, int E) {
    const int b = blockIdx.x, tid = threadIdx.x;
    const int base = b * 2048;
    __shared__ int buf[2048];
    __shared__ int ts[256];
    __shared__ int blk_prefix;
    if (tid == 0) {
        int p = 0;
        for (int i = 0; i < b; ++i) p += bsum[i];
        blk_prefix = p;
    }
    for (int i = tid; i < 2048; i += 256)
        buf[i] = (base + i < n) ? deg[base + i] : 0;
    __syncthreads();
    int local[8];
    int s = 0;
#pragma unroll
    for (int j = 0; j < 8; ++j) { local[j] = s; s += buf[tid * 8 + j]; }
    ts[tid] = s; __syncthreads();
    for (int off = 1; off < 256; off <<= 1) {
        int v = (tid >= off) ? ts[tid - off] : 0;
        __syncthreads();
        ts[tid] += v;
        __syncthreads();
    }
    const int prefix = blk_prefix + ((tid == 0) ? 0 : ts[tid - 1]);
#pragma unroll
    for (int j = 0; j < 8; ++j) {
        int idx = base + tid * 8 + j;
        if (idx < n) row_ptr[idx] = prefix + local[j];
    }
    if (b == 0 && tid == 0) row_ptr[n] = E;
}

__global__ void scatter_k(const int* __restrict__ src, const int* __restrict__ dst,
                          const int* __restrict__ rank, const int* __restrict__ row_ptr,
                          int* __restrict__ col, int E) {
    for (int e = blockIdx.x * blockDim.x + threadIdx.x; e < E; e += gridDim.x * blockDim.x)
        col[row_ptr[dst[e]] + rank[e]] = src[e];
}

// ------------- agg layer 1: fp8 d=128, half-wave pair gather ---------------
// col indices stay scalar (uniform j); half-waves take alternate neighbors.
template <int UNP>
__device__ __forceinline__ int agg1_stage(const unsigned char* __restrict__ X8,
                                          const int* __restrict__ col,
                                          int j, int e, int sel, int l32, float* acc) {
    for (; j + 2 * UNP <= e; j += 2 * UNP) {
        int c0[UNP], c1[UNP];
#pragma unroll
        for (int u = 0; u < UNP; ++u) { c0[u] = col[j + 2 * u]; c1[u] = col[j + 2 * u + 1]; }
        unsigned int vals[UNP];
#pragma unroll
        for (int u = 0; u < UNP; ++u) {
            const int cs = sel ? c1[u] : c0[u];
            vals[u] = *(const unsigned int*)(X8 + (size_t)cs * 128 + l32 * 4);
        }
#pragma unroll
        for (int u = 0; u < UNP; ++u) {
            __hip_fp8x4_e4m3 p;
            p.__x = vals[u];
            float4 f = (float4)p;
            acc[0] += f.x; acc[1] += f.y; acc[2] += f.z; acc[3] += f.w;
        }
    }
    return j;
}

__global__ __launch_bounds__(256) void aggregate1_k(
    const unsigned char* __restrict__ X8, const int* __restrict__ col,
    const int* __restrict__ rp, unsigned short* __restrict__ out, int Mnodes) {
    int node = __builtin_amdgcn_readfirstlane((blockIdx.x << 2) + (threadIdx.x >> 6));
    if (node >= Mnodes) return;
    const int lane = threadIdx.x & 63;
    const int sel = lane >> 5;
    const int l32 = lane & 31;
    const int s = rp[node], e = rp[node + 1];
    float acc[4] = {0.f, 0.f, 0.f, 0.f};

    int j = s;
    j = agg1_stage<4>(X8, col, j, e, sel, l32, acc);   // 8 neighbors/iter
    j = agg1_stage<2>(X8, col, j, e, sel, l32, acc);
    j = agg1_stage<1>(X8, col, j, e, sel, l32, acc);
    if (j < e) {
        const int c0 = col[j];
        if (sel == 0) {
            unsigned int v = *(const unsigned int*)(X8 + (size_t)c0 * 128 + l32 * 4);
            __hip_fp8x4_e4m3 p;
            p.__x = v;
            float4 f = (float4)p;
            acc[0] += f.x; acc[1] += f.y; acc[2] += f.z; acc[3] += f.w;
        }
    }
#pragma unroll
    for (int k = 0; k < 4; ++k) acc[k] += __shfl_xor(acc[k], 32, 64);
    const float inv = 1.f / fmaxf((float)(e - s), 1.f);
    if (sel == 0) {
        ushort4 o;
        o.x = f2bf(acc[0] * inv); o.y = f2bf(acc[1] * inv);
        o.z = f2bf(acc[2] * inv); o.w = f2bf(acc[3] * inv);
        *(ushort4*)(out + (size_t)node * 128 + l32 * 4) = o;
    }
}

// ------------- agg layer 2: fp8 d=256, full-wave (R11-proven) --------------
template <int UN>
__device__ __forceinline__ int agg_stage_fp8(const unsigned char* __restrict__ X8,
                                             const int* __restrict__ col,
                                             int j, int e, int lane, float* acc) {
    for (; j + UN <= e; j += UN) {
        int cs[UN];
#pragma unroll
        for (int u = 0; u < UN; ++u) cs[u] = col[j + u];
        unsigned int vals[UN];
#pragma unroll
        for (int u = 0; u < UN; ++u)
            vals[u] = *(const unsigned int*)(X8 + (size_t)cs[u] * 256 + lane * 4);
#pragma unroll
        for (int u = 0; u < UN; ++u) {
            __hip_fp8x4_e4m3 p;
            p.__x = vals[u];
            float4 f = (float4)p;
            acc[0] += f.x; acc[1] += f.y; acc[2] += f.z; acc[3] += f.w;
        }
    }
    return j;
}

__global__ __launch_bounds__(256) void aggregate2_k(
    const unsigned char* __restrict__ X8, const int* __restrict__ col,
    const int* __restrict__ rp, unsigned short* __restrict__ out, int Mnodes) {
    int node = __builtin_amdgcn_readfirstlane((blockIdx.x << 2) + (threadIdx.x >> 6));
    if (node >= Mnodes) return;
    const int lane = threadIdx.x & 63;
    const int s = rp[node], e = rp[node + 1];
    float acc[4] = {0.f, 0.f, 0.f, 0.f};

    int j = s;
    j = agg_stage_fp8<8>(X8, col, j, e, lane, acc);
    j = agg_stage_fp8<4>(X8, col, j, e, lane, acc);
    j = agg_stage_fp8<2>(X8, col, j, e, lane, acc);
    j = agg_stage_fp8<1>(X8, col, j, e, lane, acc);

    const float inv = 1.f / fmaxf((float)(e - s), 1.f);
    ushort4 o;
    o.x = f2bf(acc[0] * inv); o.y = f2bf(acc[1] * inv);
    o.z = f2bf(acc[2] * inv); o.w = f2bf(acc[3] * inv);
    *(ushort4*)(out + (size_t)node * 256 + lane * 4) = o;
}

// ---------------- dual-input bf16 MFMA GEMM, block tile 128 x 256 ----------
template <int K, bool HEAD>
__global__ __launch_bounds__(256, 2) void gemm_mfma_k(
    const unsigned short* __restrict__ A1, const unsigned short* __restrict__ W1,
    const unsigned short* __restrict__ A2, const unsigned short* __restrict__ W2,
    const float* __restrict__ bias, unsigned short* __restrict__ Hout,
    unsigned char* __restrict__ Hout8,
    const float* __restrict__ hw, const float* __restrict__ hb,
    float* __restrict__ out, int M) {
    __shared__ __align__(16) unsigned short sA[128 * 40];
    __shared__ __align__(16) unsigned short sB[256 * 40];
    __shared__ float head_acc[128];

    const int tid = threadIdx.x;
    const int wave = tid >> 6;
    const int lane = tid & 63;
    const int c = lane & 15;
    const int q = lane >> 4;
    const int m0 = blockIdx.x * 128;

    if (HEAD && tid < 128) head_acc[tid] = 0.f;  // ordered by first k-loop barrier

    floatx4 acc[8][4];
#pragma unroll
    for (int mi = 0; mi < 8; ++mi)
#pragma unroll
        for (int ni = 0; ni < 4; ++ni) acc[mi][ni] = (floatx4){0.f, 0.f, 0.f, 0.f};

    const int arow = tid >> 1;          // 0..127
    const int aseg = (tid & 1) * 16;    // 0 or 16 (ushorts)
    const int brow = tid >> 2;          // 0..63
    const int bseg = (tid & 3) * 8;
    int gr = m0 + arow;
    if (gr >= M) gr = M - 1;            // clamp; stores guarded

    for (int phase = 0; phase < 2; ++phase) {
        const unsigned short* Ap = phase ? A2 : A1;
        const unsigned short* Wp = phase ? W2 : W1;
        for (int k0 = 0; k0 < K; k0 += 32) {
            short8 va0 = *(const short8*)(Ap + (size_t)gr * K + k0 + aseg);
            short8 va1 = *(const short8*)(Ap + (size_t)gr * K + k0 + aseg + 8);
            short8 vb[4];
#pragma unroll
            for (int i = 0; i < 4; ++i)
                vb[i] = *(const short8*)(Wp + (size_t)(brow + i * 64) * K + k0 + bseg);
            __syncthreads();
            *(short8*)&sA[arow * 40 + aseg] = va0;
            *(short8*)&sA[arow * 40 + aseg + 8] = va1;
#pragma unroll
            for (int i = 0; i < 4; ++i)
                *(short8*)&sB[(brow + i * 64) * 40 + bseg] = vb[i];
            __syncthreads();

            short8 af[8], bf[4];
#pragma unroll
            for (int mi = 0; mi < 8; ++mi)
                af[mi] = *(const short8*)&sA[(mi * 16 + c) * 40 + q * 8];
#pragma unroll
            for (int ni = 0; ni < 4; ++ni)
                bf[ni] = *(const short8*)&sB[(wave * 64 + ni * 16 + c) * 40 + q * 8];
#pragma unroll
            for (int mi = 0; mi < 8; ++mi)
#pragma unroll
                for (int ni = 0; ni < 4; ++ni)
                    acc[mi][ni] = __builtin_amdgcn_mfma_f32_16x16x32_bf16(
                        af[mi], bf[ni], acc[mi][ni], 0, 0, 0);
        }
    }

    if (!HEAD) {
#pragma unroll
        for (int mi = 0; mi < 8; ++mi)
#pragma unroll
            for (int ni = 0; ni < 4; ++ni) {
                const int n = wave * 64 + ni * 16 + c;
                const float bv = bias[n];
#pragma unroll
                for (int reg = 0; reg < 4; ++reg) {
                    const int m = m0 + mi * 16 + q * 4 + reg;
                    if (m < M) {
                        float v = fmaxf(acc[mi][ni][reg] + bv, 0.f);
                        Hout[(size_t)m * 256 + n] = f2bf(v);
                        Hout8[(size_t)m * 256 + n] = f2fp8(v);
                    }
                }
            }
    } else {
#pragma unroll
        for (int mi = 0; mi < 8; ++mi) {
            float p[4] = {0.f, 0.f, 0.f, 0.f};
#pragma unroll
            for (int ni = 0; ni < 4; ++ni) {
                const int n = wave * 64 + ni * 16 + c;
                const float bv = bias[n];
                const float hv = hw[n];
#pragma unroll
                for (int reg = 0; reg < 4; ++reg)
                    p[reg] += fmaxf(acc[mi][ni][reg] + bv, 0.f) * hv;
            }
#pragma unroll
            for (int reg = 0; reg < 4; ++reg) {
                float v = p[reg];
                v += __shfl_xor(v, 1, 64);
                v += __shfl_xor(v, 2, 64);
                v += __shfl_xor(v, 4, 64);
                v += __shfl_xor(v, 8, 64);
                if (c == 0) atomicAdd(&head_acc[mi * 16 + q * 4 + reg], v);
            }
        }
        __syncthreads();
        if (tid < 128) {
            const int m = m0 + tid;
            if (m < M) out[m] = head_acc[tid] + hb[0];
        }
    }
}

// ---------------- launch ----------------
extern "C" void kernel_launch(void* const* d_in, const int* in_sizes, int n_in,
                              void* d_out, int out_size, void* d_ws, size_t ws_size,
                              hipStream_t stream) {
    const float* x    = (const float*)d_in[0];
    const int*   ei   = (const int*)d_in[1];
    const float* W1l  = (const float*)d_in[2];
    const float* b1   = (const float*)d_in[3];
    const float* W1r  = (const float*)d_in[4];
    const float* W2l  = (const float*)d_in[5];
    const float* b2   = (const float*)d_in[6];
    const float* W2r  = (const float*)d_in[7];
    const float* hw   = (const float*)d_in[8];
    const float* hb   = (const float*)d_in[9];
    float* out = (float*)d_out;

    const int M = in_sizes[0] / D_IN;       // 50000
    const int E = in_sizes[1] / 2;          // 800000
    const int* src = ei;
    const int* dst = ei + E;

    size_t off = 0;
    auto alloc = [&](size_t bytes) -> void* {
        void* p = (char*)d_ws + off;
        off += (bytes + 255) & ~(size_t)255;
        return p;
    };
    int* deg  = (int*)alloc((size_t)M * 4);
    int* rp   = (int*)alloc((size_t)(M + 1) * 4);
    int* bsum = (int*)alloc(256 * 4);
    int* rank = (int*)alloc((size_t)E * 4);
    int* col  = (int*)alloc((size_t)E * 4);
    unsigned short* xb    = (unsigned short*)alloc((size_t)M * D_IN * 2);
    unsigned char*  xb8   = (unsigned char*)alloc((size_t)M * D_IN);
    unsigned short* w1lb  = (unsigned short*)alloc((size_t)D_H * D_IN * 2);
    unsigned short* w1rb  = (unsigned short*)alloc((size_t)D_H * D_IN * 2);
    unsigned short* w2lb  = (unsigned short*)alloc((size_t)D_H * D_H * 2);
    unsigned short* w2rb  = (unsigned short*)alloc((size_t)D_H * D_H * 2);
    unsigned short* mean1 = (unsigned short*)alloc((size_t)M * D_IN * 2);
    unsigned short* h1    = (unsigned short*)alloc((size_t)M * D_H * 2);
    unsigned char*  h8    = (unsigned char*)alloc((size_t)M * D_H);
    unsigned short* mean2 = (unsigned short*)alloc((size_t)M * D_H * 2);

    hipMemsetAsync(deg, 0, (size_t)M * 4, stream);

    // fused histogram + conversions
    const int nx4 = (M * D_IN) / 4;
    const int nw14 = (D_H * D_IN) / 4;
    const int nw24 = (D_H * D_H) / 4;
    const int tot4 = nx4 + 2 * nw14 + 2 * nw24;
    const int convblk = (tot4 + 255) / 256;
    hist_conv_k<<<512 + convblk, 256, 0, stream>>>(
        dst, deg, rank, E,
        x, xb, xb8, nx4, W1l, w1lb, W1r, w1rb, nw14, W2l, w2lb, W2r, w2rb, nw24);

    // scan + scatter
    const int nseg = (M + 2047) / 2048;     // 25
    scan_part_k<<<nseg, 256, 0, stream>>>(deg, bsum, M);
    scan_final_k<<<nseg, 256, 0, stream>>>(deg, bsum, rp, M, E);
    scatter_k<<<512, 256, 0, stream>>>(src, dst, rank, rp, col, E);

    const int nblk = (M + 127) / 128;
    const int ablk = (M + 3) / 4;

    // layer 1 (gather from fp8 xb8; self path bf16 xb)
    aggregate1_k<<<ablk, 256, 0, stream>>>(xb8, col, rp, mean1, M);
    gemm_mfma_k<D_IN, false><<<nblk, 256, 0, stream>>>(
        mean1, w1lb, xb, w1rb, b1, h1, h8, nullptr, nullptr, nullptr, M);

    // layer 2 + fused head (gather from fp8 h8; self path bf16 h1)
    aggregate2_k<<<ablk, 256, 0, stream>>>(h8, col, rp, mean2, M);
    gemm_mfma_k<D_H, true><<<nblk, 256, 0, stream>>>(
        mean2, w2lb, h1, w2rb, b2, nullptr, nullptr, hw, hb, out, M);
}

// Round 14
// 247.099 us; speedup vs baseline: 1.0304x; 1.0034x over previous
//
#include <hip/hip_runtime.h>
#include <hip/hip_bf16.h>
#include <hip/hip_fp8.h>

#define D_IN 128
#define D_H  256

typedef __attribute__((ext_vector_type(8))) short short8;   // 8 bf16 (4 VGPRs)
typedef __attribute__((ext_vector_type(4))) float floatx4;  // MFMA C/D frag

__device__ __forceinline__ unsigned short f2bf(float f) {
    __hip_bfloat16 h = __float2bfloat16(f);
    return *reinterpret_cast<unsigned short*>(&h);
}
__device__ __forceinline__ float bf2f(unsigned short s) {
    union { unsigned int u; float f; } v;
    v.u = ((unsigned int)s) << 16;
    return v.f;
}
__device__ __forceinline__ unsigned char f2fp8(float f) {
    __hip_fp8_e4m3 t(f);
    return (unsigned char)t.__x;
}

// ------------- fused: histogram (+rank) AND fp32->bf16/fp8 conversions -----
__global__ void hist_conv_k(const int* __restrict__ dst, int* __restrict__ deg,
                            int* __restrict__ rank, int E,
                            const float* __restrict__ x, unsigned short* __restrict__ xb,
                            unsigned char* __restrict__ xb8, int nx4,
                            const float* __restrict__ w1l, unsigned short* __restrict__ w1lb,
                            const float* __restrict__ w1r, unsigned short* __restrict__ w1rb, int nw14,
                            const float* __restrict__ w2l, unsigned short* __restrict__ w2lb,
                            const float* __restrict__ w2r, unsigned short* __restrict__ w2rb, int nw24) {
    if (blockIdx.x < 512) {
        for (int e = blockIdx.x * 256 + threadIdx.x; e < E; e += 512 * 256)
            rank[e] = atomicAdd(&deg[dst[e]], 1);
        return;
    }
    int i = (blockIdx.x - 512) * 256 + threadIdx.x;
    if (i < nx4) {
        float4 v = ((const float4*)x)[i];
        ushort4 u;
        u.x = f2bf(v.x); u.y = f2bf(v.y); u.z = f2bf(v.z); u.w = f2bf(v.w);
        ((ushort4*)xb)[i] = u;
        uchar4 c;
        c.x = f2fp8(v.x); c.y = f2fp8(v.y); c.z = f2fp8(v.z); c.w = f2fp8(v.w);
        ((uchar4*)xb8)[i] = c;
        return;
    }
    i -= nx4;
    const float* s; unsigned short* d; int k;
    if (i < nw14) { s = w1l; d = w1lb; k = i; }
    else {
        i -= nw14;
        if (i < nw14) { s = w1r; d = w1rb; k = i; }
        else {
            i -= nw14;
            if (i < nw24) { s = w2l; d = w2lb; k = i; }
            else {
                i -= nw24;
                if (i >= nw24) return;
                s = w2r; d = w2rb; k = i;
            }
        }
    }
    float4 v = ((const float4*)s)[k];
    ushort4 u;
    u.x = f2bf(v.x); u.y = f2bf(v.y); u.z = f2bf(v.z); u.w = f2bf(v.w);
    ((ushort4*)d)[k] = u;
}

__global__ __launch_bounds__(256) void scan_part_k(const int* __restrict__ deg,
                                                   int* __restrict__ bsum, int n) {
    const int b = blockIdx.x, tid = threadIdx.x;
    const int base = b * 2048;
    const int lim = min(base + 2048, n);
    int s = 0;
    for (int i = base + tid; i < lim; i += 256) s += deg[i];
    __shared__ int red[256];
    red[tid] = s; __syncthreads();
    for (int off = 128; off > 0; off >>= 1) {
        if (tid < off) red[tid] += red[tid + off];
        __syncthreads();
    }
    if (tid == 0) bsum[b] = red[0];
}

__global__ __launch_bounds__(256) void scan_final_k(const int* __restrict__ deg,
                                                    const int* __restrict__ bsum,
                                                    int* __restrict__ row_ptr,
                                                    int n, int E) {
    const int b = blockIdx.x, tid = threadIdx.x;
    const int base = b * 2048;
    __shared__ int buf[2048];
    __shared__ int ts[256];
    __shared__ int blk_prefix;
    if (tid == 0) {
        int p = 0;
        for (int i = 0; i < b; ++i) p += bsum[i];
        blk_prefix = p;
    }
    for (int i = tid; i < 2048; i += 256)
        buf[i] = (base + i < n) ? deg[base + i] : 0;
    __syncthreads();
    int local[8];
    int s = 0;
#pragma unroll
    for (int j = 0; j < 8; ++j) { local[j] = s; s += buf[tid * 8 + j]; }
    ts[tid] = s; __syncthreads();
    for (int off = 1; off < 256; off <<= 1) {
        int v = (tid >= off) ? ts[tid - off] : 0;
        __syncthreads();
        ts[tid] += v;
        __syncthreads();
    }
    const int prefix = blk_prefix + ((tid == 0) ? 0 : ts[tid - 1]);
#pragma unroll
    for (int j = 0; j < 8; ++j) {
        int idx = base + tid * 8 + j;
        if (idx < n) row_ptr[idx] = prefix + local[j];
    }
    if (b == 0 && tid == 0) row_ptr[n] = E;
}

__global__ void scatter_k(const int* __restrict__ src, const int* __restrict__ dst,
                          const int* __restrict__ rank, const int* __restrict__ row_ptr,
                          int* __restrict__ col, int E) {
    for (int e = blockIdx.x * blockDim.x + threadIdx.x; e < E; e += gridDim.x * blockDim.x)
        col[row_ptr[dst[e]] + rank[e]] = src[e];
}

// ------------- agg layer 1: fp8 d=128, half-wave pair gather ---------------
template <int UNP>
__device__ __forceinline__ int agg1_stage(const unsigned char* __restrict__ X8,
                                          const int* __restrict__ col,
                                          int j, int e, int sel, int l32, float* acc) {
    for (; j + 2 * UNP <= e; j += 2 * UNP) {
        int c0[UNP], c1[UNP];
#pragma unroll
        for (int u = 0; u < UNP; ++u) { c0[u] = col[j + 2 * u]; c1[u] = col[j + 2 * u + 1]; }
        unsigned int vals[UNP];
#pragma unroll
        for (int u = 0; u < UNP; ++u) {
            const int cs = sel ? c1[u] : c0[u];
            vals[u] = *(const unsigned int*)(X8 + (size_t)cs * 128 + l32 * 4);
        }
#pragma unroll
        for (int u = 0; u < UNP; ++u) {
            __hip_fp8x4_e4m3 p;
            p.__x = vals[u];
            float4 f = (float4)p;
            acc[0] += f.x; acc[1] += f.y; acc[2] += f.z; acc[3] += f.w;
        }
    }
    return j;
}

__global__ __launch_bounds__(256) void aggregate1_k(
    const unsigned char* __restrict__ X8, const int* __restrict__ col,
    const int* __restrict__ rp, unsigned short* __restrict__ out, int Mnodes) {
    int node = __builtin_amdgcn_readfirstlane((blockIdx.x << 2) + (threadIdx.x >> 6));
    if (node >= Mnodes) return;
    const int lane = threadIdx.x & 63;
    const int sel = lane >> 5;
    const int l32 = lane & 31;
    const int s = rp[node], e = rp[node + 1];
    float acc[4] = {0.f, 0.f, 0.f, 0.f};

    int j = s;
    j = agg1_stage<4>(X8, col, j, e, sel, l32, acc);
    j = agg1_stage<2>(X8, col, j, e, sel, l32, acc);
    j = agg1_stage<1>(X8, col, j, e, sel, l32, acc);
    if (j < e) {
        const int c0 = col[j];
        if (sel == 0) {
            unsigned int v = *(const unsigned int*)(X8 + (size_t)c0 * 128 + l32 * 4);
            __hip_fp8x4_e4m3 p;
            p.__x = v;
            float4 f = (float4)p;
            acc[0] += f.x; acc[1] += f.y; acc[2] += f.z; acc[3] += f.w;
        }
    }
#pragma unroll
    for (int k = 0; k < 4; ++k) acc[k] += __shfl_xor(acc[k], 32, 64);
    const float inv = 1.f / fmaxf((float)(e - s), 1.f);
    if (sel == 0) {
        ushort4 o;
        o.x = f2bf(acc[0] * inv); o.y = f2bf(acc[1] * inv);
        o.z = f2bf(acc[2] * inv); o.w = f2bf(acc[3] * inv);
        *(ushort4*)(out + (size_t)node * 128 + l32 * 4) = o;
    }
}

// ------------- agg layer 2: fp8 d=256, full-wave (R11-proven) --------------
template <int UN>
__device__ __forceinline__ int agg_stage_fp8(const unsigned char* __restrict__ X8,
                                             const int* __restrict__ col,
                                             int j, int e, int lane, float* acc) {
    for (; j + UN <= e; j += UN) {
        int cs[UN];
#pragma unroll
        for (int u = 0; u < UN; ++u) cs[u] = col[j + u];
        unsigned int vals[UN];
#pragma unroll
        for (int u = 0; u < UN; ++u)
            vals[u] = *(const unsigned int*)(X8 + (size_t)cs[u] * 256 + lane * 4);
#pragma unroll
        for (int u = 0; u < UN; ++u) {
            __hip_fp8x4_e4m3 p;
            p.__x = vals[u];
            float4 f = (float4)p;
            acc[0] += f.x; acc[1] += f.y; acc[2] += f.z; acc[3] += f.w;
        }
    }
    return j;
}

__global__ __launch_bounds__(256) void aggregate2_k(
    const unsigned char* __restrict__ X8, const int* __restrict__ col,
    const int* __restrict__ rp, unsigned short* __restrict__ out, int Mnodes) {
    int node = __builtin_amdgcn_readfirstlane((blockIdx.x << 2) + (threadIdx.x >> 6));
    if (node >= Mnodes) return;
    const int lane = threadIdx.x & 63;
    const int s = rp[node], e = rp[node + 1];
    float acc[4] = {0.f, 0.f, 0.f, 0.f};

    int j = s;
    j = agg_stage_fp8<8>(X8, col, j, e, lane, acc);
    j = agg_stage_fp8<4>(X8, col, j, e, lane, acc);
    j = agg_stage_fp8<2>(X8, col, j, e, lane, acc);
    j = agg_stage_fp8<1>(X8, col, j, e, lane, acc);

    const float inv = 1.f / fmaxf((float)(e - s), 1.f);
    ushort4 o;
    o.x = f2bf(acc[0] * inv); o.y = f2bf(acc[1] * inv);
    o.z = f2bf(acc[2] * inv); o.w = f2bf(acc[3] * inv);
    *(ushort4*)(out + (size_t)node * 256 + lane * 4) = o;
}

// ---------------- dual-input bf16 MFMA GEMM, 128x256, reg double-buffer ----
// K-loop flattened over both phases; chunk t+1's global loads are issued
// between the LDS-write and the consume-barrier so they overlap chunk t's
// MFMA work (register double-buffering of the staging loads).
template <int K, bool HEAD>
__global__ __launch_bounds__(256, 2) void gemm_mfma_k(
    const unsigned short* __restrict__ A1, const unsigned short* __restrict__ W1,
    const unsigned short* __restrict__ A2, const unsigned short* __restrict__ W2,
    const float* __restrict__ bias, unsigned short* __restrict__ Hout,
    unsigned char* __restrict__ Hout8,
    const float* __restrict__ hw, const float* __restrict__ hb,
    float* __restrict__ out, int M) {
    __shared__ __align__(16) unsigned short sA[128 * 40];
    __shared__ __align__(16) unsigned short sB[256 * 40];
    __shared__ float head_acc[128];

    constexpr int NCK = K / 32;          // chunks per phase
    constexpr int NC = 2 * NCK;          // total chunks

    const int tid = threadIdx.x;
    const int wave = tid >> 6;
    const int lane = tid & 63;
    const int c = lane & 15;
    const int q = lane >> 4;
    const int m0 = blockIdx.x * 128;

    if (HEAD && tid < 128) head_acc[tid] = 0.f;  // ordered by first k-loop barrier

    floatx4 acc[8][4];
#pragma unroll
    for (int mi = 0; mi < 8; ++mi)
#pragma unroll
        for (int ni = 0; ni < 4; ++ni) acc[mi][ni] = (floatx4){0.f, 0.f, 0.f, 0.f};

    const int arow = tid >> 1;          // 0..127
    const int aseg = (tid & 1) * 16;    // 0 or 16 (ushorts)
    const int brow = tid >> 2;          // 0..63
    const int bseg = (tid & 3) * 8;
    int gr = m0 + arow;
    if (gr >= M) gr = M - 1;            // clamp; stores guarded

    auto loadChunk = [&](int t, short8& a0, short8& a1, short8* b) {
        const unsigned short* Ap = (t >= NCK) ? A2 : A1;
        const unsigned short* Wp = (t >= NCK) ? W2 : W1;
        const int k0 = (t & (NCK - 1)) * 32;
        a0 = *(const short8*)(Ap + (size_t)gr * K + k0 + aseg);
        a1 = *(const short8*)(Ap + (size_t)gr * K + k0 + aseg + 8);
#pragma unroll
        for (int i = 0; i < 4; ++i)
            b[i] = *(const short8*)(Wp + (size_t)(brow + i * 64) * K + k0 + bseg);
    };

    short8 ca0, ca1, cb[4], na0, na1, nb[4];
    loadChunk(0, ca0, ca1, cb);

#pragma unroll 1
    for (int t = 0; t < NC; ++t) {
        __syncthreads();                // prev chunk's frag reads done
        *(short8*)&sA[arow * 40 + aseg] = ca0;
        *(short8*)&sA[arow * 40 + aseg + 8] = ca1;
#pragma unroll
        for (int i = 0; i < 4; ++i)
            *(short8*)&sB[(brow + i * 64) * 40 + bseg] = cb[i];
        if (t + 1 < NC)
            loadChunk(t + 1, na0, na1, nb);     // in flight across MFMA below
        __syncthreads();                // LDS writes visible

        short8 af[8], bf[4];
#pragma unroll
        for (int mi = 0; mi < 8; ++mi)
            af[mi] = *(const short8*)&sA[(mi * 16 + c) * 40 + q * 8];
#pragma unroll
        for (int ni = 0; ni < 4; ++ni)
            bf[ni] = *(const short8*)&sB[(wave * 64 + ni * 16 + c) * 40 + q * 8];
#pragma unroll
        for (int mi = 0; mi < 8; ++mi)
#pragma unroll
            for (int ni = 0; ni < 4; ++ni)
                acc[mi][ni] = __builtin_amdgcn_mfma_f32_16x16x32_bf16(
                    af[mi], bf[ni], acc[mi][ni], 0, 0, 0);

        ca0 = na0; ca1 = na1;
#pragma unroll
        for (int i = 0; i < 4; ++i) cb[i] = nb[i];
    }

    if (!HEAD) {
#pragma unroll
        for (int mi = 0; mi < 8; ++mi)
#pragma unroll
            for (int ni = 0; ni < 4; ++ni) {
                const int n = wave * 64 + ni * 16 + c;
                const float bv = bias[n];
#pragma unroll
                for (int reg = 0; reg < 4; ++reg) {
                    const int m = m0 + mi * 16 + q * 4 + reg;
                    if (m < M) {
                        float v = fmaxf(acc[mi][ni][reg] + bv, 0.f);
                        Hout[(size_t)m * 256 + n] = f2bf(v);
                        Hout8[(size_t)m * 256 + n] = f2fp8(v);
                    }
                }
            }
    } else {
#pragma unroll
        for (int mi = 0; mi < 8; ++mi) {
            float p[4] = {0.f, 0.f, 0.f, 0.f};
#pragma unroll
            for (int ni = 0; ni < 4; ++ni) {
                const int n = wave * 64 + ni * 16 + c;
                const float bv = bias[n];
                const float hv = hw[n];
#pragma unroll
                for (int reg = 0; reg < 4; ++reg)
                    p[reg] += fmaxf(acc[mi][ni][reg] + bv, 0.f) * hv;
            }
#pragma unroll
            for (int reg = 0; reg < 4; ++reg) {
                float v = p[reg];
                v += __shfl_xor(v, 1, 64);
                v += __shfl_xor(v, 2, 64);
                v += __shfl_xor(v, 4, 64);
                v += __shfl_xor(v, 8, 64);
                if (c == 0) atomicAdd(&head_acc[mi * 16 + q * 4 + reg], v);
            }
        }
        __syncthreads();
        if (tid < 128) {
            const int m = m0 + tid;
            if (m < M) out[m] = head_acc[tid] + hb[0];
        }
    }
}

// ---------------- launch ----------------
extern "C" void kernel_launch(void* const* d_in, const int* in_sizes, int n_in,
                              void* d_out, int out_size, void* d_ws, size_t ws_size,
                              hipStream_t stream) {
    const float* x    = (const float*)d_in[0];
    const int*   ei   = (const int*)d_in[1];
    const float* W1l  = (const float*)d_in[2];
    const float* b1   = (const float*)d_in[3];
    const float* W1r  = (const float*)d_in[4];
    const float* W2l  = (const float*)d_in[5];
    const float* b2   = (const float*)d_in[6];
    const float* W2r  = (const float*)d_in[7];
    const float* hw   = (const float*)d_in[8];
    const float* hb   = (const float*)d_in[9];
    float* out = (float*)d_out;

    const int M = in_sizes[0] / D_IN;       // 50000
    const int E = in_sizes[1] / 2;          // 800000
    const int* src = ei;
    const int* dst = ei + E;

    size_t off = 0;
    auto alloc = [&](size_t bytes) -> void* {
        void* p = (char*)d_ws + off;
        off += (bytes + 255) & ~(size_t)255;
        return p;
    };
    int* deg  = (int*)alloc((size_t)M * 4);
    int* rp   = (int*)alloc((size_t)(M + 1) * 4);
    int* bsum = (int*)alloc(256 * 4);
    int* rank = (int*)alloc((size_t)E * 4);
    int* col  = (int*)alloc((size_t)E * 4);
    unsigned short* xb    = (unsigned short*)alloc((size_t)M * D_IN * 2);
    unsigned char*  xb8   = (unsigned char*)alloc((size_t)M * D_IN);
    unsigned short* w1lb  = (unsigned short*)alloc((size_t)D_H * D_IN * 2);
    unsigned short* w1rb  = (unsigned short*)alloc((size_t)D_H * D_IN * 2);
    unsigned short* w2lb  = (unsigned short*)alloc((size_t)D_H * D_H * 2);
    unsigned short* w2rb  = (unsigned short*)alloc((size_t)D_H * D_H * 2);
    unsigned short* mean1 = (unsigned short*)alloc((size_t)M * D_IN * 2);
    unsigned short* h1    = (unsigned short*)alloc((size_t)M * D_H * 2);
    unsigned char*  h8    = (unsigned char*)alloc((size_t)M * D_H);
    unsigned short* mean2 = (unsigned short*)alloc((size_t)M * D_H * 2);

    hipMemsetAsync(deg, 0, (size_t)M * 4, stream);

    // fused histogram + conversions
    const int nx4 = (M * D_IN) / 4;
    const int nw14 = (D_H * D_IN) / 4;
    const int nw24 = (D_H * D_H) / 4;
    const int tot4 = nx4 + 2 * nw14 + 2 * nw24;
    const int convblk = (tot4 + 255) / 256;
    hist_conv_k<<<512 + convblk, 256, 0, stream>>>(
        dst, deg, rank, E,
        x, xb, xb8, nx4, W1l, w1lb, W1r, w1rb, nw14, W2l, w2lb, W2r, w2rb, nw24);

    // scan + scatter
    const int nseg = (M + 2047) / 2048;     // 25
    scan_part_k<<<nseg, 256, 0, stream>>>(deg, bsum, M);
    scan_final_k<<<nseg, 256, 0, stream>>>(deg, bsum, rp, M, E);
    scatter_k<<<512, 256, 0, stream>>>(src, dst, rank, rp, col, E);

    const int nblk = (M + 127) / 128;
    const int ablk = (M + 3) / 4;

    // layer 1 (gather from fp8 xb8; self path bf16 xb)
    aggregate1_k<<<ablk, 256, 0, stream>>>(xb8, col, rp, mean1, M);
    gemm_mfma_k<D_IN, false><<<nblk, 256, 0, stream>>>(
        mean1, w1lb, xb, w1rb, b1, h1, h8, nullptr, nullptr, nullptr, M);

    // layer 2 + fused head (gather from fp8 h8; self path bf16 h1)
    aggregate2_k<<<ablk, 256, 0, stream>>>(h8, col, rp, mean2, M);
    gemm_mfma_k<D_H, true><<<nblk, 256, 0, stream>>>(
        mean2, w2lb, h1, w2rb, b2, nullptr, nullptr, hw, hb, out, M);
}

// Round 15
// 232.788 us; speedup vs baseline: 1.0938x; 1.0615x over previous
//
#include <hip/hip_runtime.h>
#include <hip/hip_bf16.h>
#include <hip/hip_fp8.h>

#define D_IN 128
#define D_H  256
#define NBLK 128            // edge-chunk blocks for hist/place (must match!)
#define BSH  7              // 128 nodes per bucket
#define BNODES 128

typedef __attribute__((ext_vector_type(8))) short short8;   // 8 bf16 (4 VGPRs)
typedef __attribute__((ext_vector_type(4))) float floatx4;  // MFMA C/D frag

__device__ __forceinline__ unsigned short f2bf(float f) {
    __hip_bfloat16 h = __float2bfloat16(f);
    return *reinterpret_cast<unsigned short*>(&h);
}
__device__ __forceinline__ float bf2f(unsigned short s) {
    union { unsigned int u; float f; } v;
    v.u = ((unsigned int)s) << 16;
    return v.f;
}
__device__ __forceinline__ unsigned char f2fp8(float f) {
    __hip_fp8_e4m3 t(f);
    return (unsigned char)t.__x;
}

// ---- P1: LDS bucket histogram (blocks < NBLK) + fp32->bf16/fp8 casts ------
// No global atomics: per-(block,bucket) counts via plain writes.
__global__ void p1_hist_conv_k(const int* __restrict__ dst, int* __restrict__ cnt2d,
                               int E, int NB,
                               const float* __restrict__ x, unsigned short* __restrict__ xb,
                               unsigned char* __restrict__ xb8, int nx4,
                               const float* __restrict__ w1l, unsigned short* __restrict__ w1lb,
                               const float* __restrict__ w1r, unsigned short* __restrict__ w1rb, int nw14,
                               const float* __restrict__ w2l, unsigned short* __restrict__ w2lb,
                               const float* __restrict__ w2r, unsigned short* __restrict__ w2rb, int nw24) {
    if (blockIdx.x < NBLK) {
        __shared__ int h[512];                  // NB <= 512
        for (int i = threadIdx.x; i < NB; i += 256) h[i] = 0;
        __syncthreads();
        for (int e = blockIdx.x * 256 + threadIdx.x; e < E; e += NBLK * 256)
            atomicAdd(&h[dst[e] >> BSH], 1);    // LDS atomic (fast)
        __syncthreads();
        for (int i = threadIdx.x; i < NB; i += 256)
            cnt2d[blockIdx.x * NB + i] = h[i];
        return;
    }
    int i = (blockIdx.x - NBLK) * 256 + threadIdx.x;
    if (i < nx4) {
        float4 v = ((const float4*)x)[i];
        ushort4 u;
        u.x = f2bf(v.x); u.y = f2bf(v.y); u.z = f2bf(v.z); u.w = f2bf(v.w);
        ((ushort4*)xb)[i] = u;
        uchar4 c;
        c.x = f2fp8(v.x); c.y = f2fp8(v.y); c.z = f2fp8(v.z); c.w = f2fp8(v.w);
        ((uchar4*)xb8)[i] = c;
        return;
    }
    i -= nx4;
    const float* s; unsigned short* d; int k;
    if (i < nw14) { s = w1l; d = w1lb; k = i; }
    else {
        i -= nw14;
        if (i < nw14) { s = w1r; d = w1rb; k = i; }
        else {
            i -= nw14;
            if (i < nw24) { s = w2l; d = w2lb; k = i; }
            else {
                i -= nw24;
                if (i >= nw24) return;
                s = w2r; d = w2rb; k = i;
            }
        }
    }
    float4 v = ((const float4*)s)[k];
    ushort4 u;
    u.x = f2bf(v.x); u.y = f2bf(v.y); u.z = f2bf(v.z); u.w = f2bf(v.w);
    ((ushort4*)d)[k] = u;
}

// ---- S1: per-bucket scan over the NBLK block counts -----------------------
__global__ __launch_bounds__(NBLK) void bucket_scan_k(const int* __restrict__ cnt2d,
                                                      int* __restrict__ off2d,
                                                      int* __restrict__ tot, int NB) {
    const int B = blockIdx.x, t = threadIdx.x;
    __shared__ int sc[NBLK];
    __shared__ int orig[NBLK];
    int v = cnt2d[t * NB + B];
    orig[t] = v; sc[t] = v;
    __syncthreads();
    for (int off = 1; off < NBLK; off <<= 1) {
        int u = (t >= off) ? sc[t - off] : 0;
        __syncthreads();
        sc[t] += u;
        __syncthreads();
    }
    off2d[t * NB + B] = sc[t] - orig[t];
    if (t == NBLK - 1) tot[B] = sc[t];
}

// ---- S2: scan bucket totals -> bases; rp[M]=E -----------------------------
__global__ __launch_bounds__(512) void base_scan_k(const int* __restrict__ tot,
                                                   int* __restrict__ base,
                                                   int* __restrict__ rp,
                                                   int NB, int M, int E) {
    __shared__ int sc[512];
    const int t = threadIdx.x;
    int v = (t < NB) ? tot[t] : 0;
    sc[t] = v;
    __syncthreads();
    for (int off = 1; off < 512; off <<= 1) {
        int u = (t >= off) ? sc[t - off] : 0;
        __syncthreads();
        sc[t] += u;
        __syncthreads();
    }
    if (t < NB) base[t] = sc[t] - v;
    if (t == NB - 1) base[NB] = sc[t];
    if (t == 0) rp[M] = E;
}

// ---- P2: place edges into bucket-grouped staging (LDS cursors only) -------
// pack = (dst&127)<<16 | src  (requires src < 65536 — N_NODES=50000 ok)
__global__ __launch_bounds__(256) void place_k(const int* __restrict__ src,
                                               const int* __restrict__ dst,
                                               const int* __restrict__ off2d,
                                               const int* __restrict__ base,
                                               unsigned int* __restrict__ staging,
                                               int E, int NB) {
    __shared__ int cur[512];
    const int b = blockIdx.x;
    for (int i = threadIdx.x; i < NB; i += 256)
        cur[i] = base[i] + off2d[b * NB + i];
    __syncthreads();
    for (int e = b * 256 + threadIdx.x; e < E; e += NBLK * 256) {
        const int d = dst[e];
        const int pos = atomicAdd(&cur[d >> BSH], 1);
        staging[pos] = ((unsigned int)(d & (BNODES - 1)) << 16) | (unsigned int)src[e];
    }
}

// ---- P3: per-bucket counting sort -> rp + col -----------------------------
__global__ __launch_bounds__(256) void bucket_sort_k(const unsigned int* __restrict__ staging,
                                                     const int* __restrict__ base,
                                                     int* __restrict__ rp, int* __restrict__ col,
                                                     int M) {
    const int B = blockIdx.x, tid = threadIdx.x;
    __shared__ int h[BNODES], sc[BNODES], cur[BNODES];
    if (tid < BNODES) h[tid] = 0;
    __syncthreads();
    const int s0 = base[B], s1 = base[B + 1];
    for (int i = s0 + tid; i < s1; i += 256)
        atomicAdd(&h[staging[i] >> 16], 1);
    __syncthreads();
    if (tid < BNODES) sc[tid] = h[tid];
    __syncthreads();
    for (int off = 1; off < BNODES; off <<= 1) {
        int v = 0;
        if (tid < BNODES && tid >= off) v = sc[tid - off];
        __syncthreads();
        if (tid < BNODES) sc[tid] += v;
        __syncthreads();
    }
    if (tid < BNODES) {
        const int excl = sc[tid] - h[tid];
        const int node = B * BNODES + tid;
        if (node < M) rp[node] = s0 + excl;
        cur[tid] = s0 + excl;
    }
    __syncthreads();
    for (int i = s0 + tid; i < s1; i += 256) {
        const unsigned int u = staging[i];
        const int pos = atomicAdd(&cur[u >> 16], 1);
        col[pos] = (int)(u & 0xFFFFu);
    }
}

// ------------- agg layer 1: fp8 d=128, half-wave pair gather ---------------
template <int UNP>
__device__ __forceinline__ int agg1_stage(const unsigned char* __restrict__ X8,
                                          const int* __restrict__ col,
                                          int j, int e, int sel, int l32, float* acc) {
    for (; j + 2 * UNP <= e; j += 2 * UNP) {
        int c0[UNP], c1[UNP];
#pragma unroll
        for (int u = 0; u < UNP; ++u) { c0[u] = col[j + 2 * u]; c1[u] = col[j + 2 * u + 1]; }
        unsigned int vals[UNP];
#pragma unroll
        for (int u = 0; u < UNP; ++u) {
            const int cs = sel ? c1[u] : c0[u];
            vals[u] = *(const unsigned int*)(X8 + (size_t)cs * 128 + l32 * 4);
        }
#pragma unroll
        for (int u = 0; u < UNP; ++u) {
            __hip_fp8x4_e4m3 p;
            p.__x = vals[u];
            float4 f = (float4)p;
            acc[0] += f.x; acc[1] += f.y; acc[2] += f.z; acc[3] += f.w;
        }
    }
    return j;
}

__global__ __launch_bounds__(256) void aggregate1_k(
    const unsigned char* __restrict__ X8, const int* __restrict__ col,
    const int* __restrict__ rp, unsigned short* __restrict__ out, int Mnodes) {
    int node = __builtin_amdgcn_readfirstlane((blockIdx.x << 2) + (threadIdx.x >> 6));
    if (node >= Mnodes) return;
    const int lane = threadIdx.x & 63;
    const int sel = lane >> 5;
    const int l32 = lane & 31;
    const int s = rp[node], e = rp[node + 1];
    float acc[4] = {0.f, 0.f, 0.f, 0.f};

    int j = s;
    j = agg1_stage<4>(X8, col, j, e, sel, l32, acc);
    j = agg1_stage<2>(X8, col, j, e, sel, l32, acc);
    j = agg1_stage<1>(X8, col, j, e, sel, l32, acc);
    if (j < e) {
        const int c0 = col[j];
        if (sel == 0) {
            unsigned int v = *(const unsigned int*)(X8 + (size_t)c0 * 128 + l32 * 4);
            __hip_fp8x4_e4m3 p;
            p.__x = v;
            float4 f = (float4)p;
            acc[0] += f.x; acc[1] += f.y; acc[2] += f.z; acc[3] += f.w;
        }
    }
#pragma unroll
    for (int k = 0; k < 4; ++k) acc[k] += __shfl_xor(acc[k], 32, 64);
    const float inv = 1.f / fmaxf((float)(e - s), 1.f);
    if (sel == 0) {
        ushort4 o;
        o.x = f2bf(acc[0] * inv); o.y = f2bf(acc[1] * inv);
        o.z = f2bf(acc[2] * inv); o.w = f2bf(acc[3] * inv);
        *(ushort4*)(out + (size_t)node * 128 + l32 * 4) = o;
    }
}

// ------------- agg layer 2: fp8 d=256, full-wave ---------------------------
template <int UN>
__device__ __forceinline__ int agg_stage_fp8(const unsigned char* __restrict__ X8,
                                             const int* __restrict__ col,
                                             int j, int e, int lane, float* acc) {
    for (; j + UN <= e; j += UN) {
        int cs[UN];
#pragma unroll
        for (int u = 0; u < UN; ++u) cs[u] = col[j + u];
        unsigned int vals[UN];
#pragma unroll
        for (int u = 0; u < UN; ++u)
            vals[u] = *(const unsigned int*)(X8 + (size_t)cs[u] * 256 + lane * 4);
#pragma unroll
        for (int u = 0; u < UN; ++u) {
            __hip_fp8x4_e4m3 p;
            p.__x = vals[u];
            float4 f = (float4)p;
            acc[0] += f.x; acc[1] += f.y; acc[2] += f.z; acc[3] += f.w;
        }
    }
    return j;
}

__global__ __launch_bounds__(256) void aggregate2_k(
    const unsigned char* __restrict__ X8, const int* __restrict__ col,
    const int* __restrict__ rp, unsigned short* __restrict__ out, int Mnodes) {
    int node = __builtin_amdgcn_readfirstlane((blockIdx.x << 2) + (threadIdx.x >> 6));
    if (node >= Mnodes) return;
    const int lane = threadIdx.x & 63;
    const int s = rp[node], e = rp[node + 1];
    float acc[4] = {0.f, 0.f, 0.f, 0.f};

    int j = s;
    j = agg_stage_fp8<8>(X8, col, j, e, lane, acc);
    j = agg_stage_fp8<4>(X8, col, j, e, lane, acc);
    j = agg_stage_fp8<2>(X8, col, j, e, lane, acc);
    j = agg_stage_fp8<1>(X8, col, j, e, lane, acc);

    const float inv = 1.f / fmaxf((float)(e - s), 1.f);
    ushort4 o;
    o.x = f2bf(acc[0] * inv); o.y = f2bf(acc[1] * inv);
    o.z = f2bf(acc[2] * inv); o.w = f2bf(acc[3] * inv);
    *(ushort4*)(out + (size_t)node * 256 + lane * 4) = o;
}

// ---------------- dual-input bf16 MFMA GEMM, 128x256, reg double-buffer ----
template <int K, bool HEAD>
__global__ __launch_bounds__(256, 2) void gemm_mfma_k(
    const unsigned short* __restrict__ A1, const unsigned short* __restrict__ W1,
    const unsigned short* __restrict__ A2, const unsigned short* __restrict__ W2,
    const float* __restrict__ bias, unsigned short* __restrict__ Hout,
    unsigned char* __restrict__ Hout8,
    const float* __restrict__ hw, const float* __restrict__ hb,
    float* __restrict__ out, int M) {
    __shared__ __align__(16) unsigned short sA[128 * 40];
    __shared__ __align__(16) unsigned short sB[256 * 40];
    __shared__ float head_acc[128];

    constexpr int NCK = K / 32;
    constexpr int NC = 2 * NCK;

    const int tid = threadIdx.x;
    const int wave = tid >> 6;
    const int lane = tid & 63;
    const int c = lane & 15;
    const int q = lane >> 4;
    const int m0 = blockIdx.x * 128;

    if (HEAD && tid < 128) head_acc[tid] = 0.f;

    floatx4 acc[8][4];
#pragma unroll
    for (int mi = 0; mi < 8; ++mi)
#pragma unroll
        for (int ni = 0; ni < 4; ++ni) acc[mi][ni] = (floatx4){0.f, 0.f, 0.f, 0.f};

    const int arow = tid >> 1;
    const int aseg = (tid & 1) * 16;
    const int brow = tid >> 2;
    const int bseg = (tid & 3) * 8;
    int gr = m0 + arow;
    if (gr >= M) gr = M - 1;

    auto loadChunk = [&](int t, short8& a0, short8& a1, short8* b) {
        const unsigned short* Ap = (t >= NCK) ? A2 : A1;
        const unsigned short* Wp = (t >= NCK) ? W2 : W1;
        const int k0 = (t & (NCK - 1)) * 32;
        a0 = *(const short8*)(Ap + (size_t)gr * K + k0 + aseg);
        a1 = *(const short8*)(Ap + (size_t)gr * K + k0 + aseg + 8);
#pragma unroll
        for (int i = 0; i < 4; ++i)
            b[i] = *(const short8*)(Wp + (size_t)(brow + i * 64) * K + k0 + bseg);
    };

    short8 ca0, ca1, cb[4], na0, na1, nb[4];
    loadChunk(0, ca0, ca1, cb);

#pragma unroll 1
    for (int t = 0; t < NC; ++t) {
        __syncthreads();
        *(short8*)&sA[arow * 40 + aseg] = ca0;
        *(short8*)&sA[arow * 40 + aseg + 8] = ca1;
#pragma unroll
        for (int i = 0; i < 4; ++i)
            *(short8*)&sB[(brow + i * 64) * 40 + bseg] = cb[i];
        if (t + 1 < NC)
            loadChunk(t + 1, na0, na1, nb);
        __syncthreads();

        short8 af[8], bf[4];
#pragma unroll
        for (int mi = 0; mi < 8; ++mi)
            af[mi] = *(const short8*)&sA[(mi * 16 + c) * 40 + q * 8];
#pragma unroll
        for (int ni = 0; ni < 4; ++ni)
            bf[ni] = *(const short8*)&sB[(wave * 64 + ni * 16 + c) * 40 + q * 8];
#pragma unroll
        for (int mi = 0; mi < 8; ++mi)
#pragma unroll
            for (int ni = 0; ni < 4; ++ni)
                acc[mi][ni] = __builtin_amdgcn_mfma_f32_16x16x32_bf16(
                    af[mi], bf[ni], acc[mi][ni], 0, 0, 0);

        ca0 = na0; ca1 = na1;
#pragma unroll
        for (int i = 0; i < 4; ++i) cb[i] = nb[i];
    }

    if (!HEAD) {
#pragma unroll
        for (int mi = 0; mi < 8; ++mi)
#pragma unroll
            for (int ni = 0; ni < 4; ++ni) {
                const int n = wave * 64 + ni * 16 + c;
                const float bv = bias[n];
#pragma unroll
                for (int reg = 0; reg < 4; ++reg) {
                    const int m = m0 + mi * 16 + q * 4 + reg;
                    if (m < M) {
                        float v = fmaxf(acc[mi][ni][reg] + bv, 0.f);
                        Hout[(size_t)m * 256 + n] = f2bf(v);
                        Hout8[(size_t)m * 256 + n] = f2fp8(v);
                    }
                }
            }
    } else {
#pragma unroll
        for (int mi = 0; mi < 8; ++mi) {
            float p[4] = {0.f, 0.f, 0.f, 0.f};
#pragma unroll
            for (int ni = 0; ni < 4; ++ni) {
                const int n = wave * 64 + ni * 16 + c;
                const float bv = bias[n];
                const float hv = hw[n];
#pragma unroll
                for (int reg = 0; reg < 4; ++reg)
                    p[reg] += fmaxf(acc[mi][ni][reg] + bv, 0.f) * hv;
            }
#pragma unroll
            for (int reg = 0; reg < 4; ++reg) {
                float v = p[reg];
                v += __shfl_xor(v, 1, 64);
                v += __shfl_xor(v, 2, 64);
                v += __shfl_xor(v, 4, 64);
                v += __shfl_xor(v, 8, 64);
                if (c == 0) atomicAdd(&head_acc[mi * 16 + q * 4 + reg], v);
            }
        }
        __syncthreads();
        if (tid < 128) {
            const int m = m0 + tid;
            if (m < M) out[m] = head_acc[tid] + hb[0];
        }
    }
}

// ---------------- launch ----------------
extern "C" void kernel_launch(void* const* d_in, const int* in_sizes, int n_in,
                              void* d_out, int out_size, void* d_ws, size_t ws_size,
                              hipStream_t stream) {
    const float* x    = (const float*)d_in[0];
    const int*   ei   = (const int*)d_in[1];
    const float* W1l  = (const float*)d_in[2];
    const float* b1   = (const float*)d_in[3];
    const float* W1r  = (const float*)d_in[4];
    const float* W2l  = (const float*)d_in[5];
    const float* b2   = (const float*)d_in[6];
    const float* W2r  = (const float*)d_in[7];
    const float* hw   = (const float*)d_in[8];
    const float* hb   = (const float*)d_in[9];
    float* out = (float*)d_out;

    const int M = in_sizes[0] / D_IN;       // 50000 (< 65536: src packs in 16b)
    const int E = in_sizes[1] / 2;          // 800000
    const int* src = ei;
    const int* dst = ei + E;
    const int NB = (M + BNODES - 1) / BNODES;   // 391 buckets

    size_t off = 0;
    auto alloc = [&](size_t bytes) -> void* {
        void* p = (char*)d_ws + off;
        off += (bytes + 255) & ~(size_t)255;
        return p;
    };
    int* cnt2d = (int*)alloc((size_t)NBLK * NB * 4);
    int* off2d = (int*)alloc((size_t)NBLK * NB * 4);
    int* tot   = (int*)alloc((size_t)NB * 4);
    int* base  = (int*)alloc((size_t)(NB + 1) * 4);
    unsigned int* staging = (unsigned int*)alloc((size_t)E * 4);
    int* rp    = (int*)alloc((size_t)(M + 1) * 4);
    int* col   = (int*)alloc((size_t)E * 4);
    unsigned short* xb    = (unsigned short*)alloc((size_t)M * D_IN * 2);
    unsigned char*  xb8   = (unsigned char*)alloc((size_t)M * D_IN);
    unsigned short* w1lb  = (unsigned short*)alloc((size_t)D_H * D_IN * 2);
    unsigned short* w1rb  = (unsigned short*)alloc((size_t)D_H * D_IN * 2);
    unsigned short* w2lb  = (unsigned short*)alloc((size_t)D_H * D_H * 2);
    unsigned short* w2rb  = (unsigned short*)alloc((size_t)D_H * D_H * 2);
    unsigned short* mean1 = (unsigned short*)alloc((size_t)M * D_IN * 2);
    unsigned short* h1    = (unsigned short*)alloc((size_t)M * D_H * 2);
    unsigned char*  h8    = (unsigned char*)alloc((size_t)M * D_H);
    unsigned short* mean2 = (unsigned short*)alloc((size_t)M * D_H * 2);

    // CSR build (atomic-free at device scope) + conversions
    const int nx4 = (M * D_IN) / 4;
    const int nw14 = (D_H * D_IN) / 4;
    const int nw24 = (D_H * D_H) / 4;
    const int tot4 = nx4 + 2 * nw14 + 2 * nw24;
    const int convblk = (tot4 + 255) / 256;
    p1_hist_conv_k<<<NBLK + convblk, 256, 0, stream>>>(
        dst, cnt2d, E, NB,
        x, xb, xb8, nx4, W1l, w1lb, W1r, w1rb, nw14, W2l, w2lb, W2r, w2rb, nw24);
    bucket_scan_k<<<NB, NBLK, 0, stream>>>(cnt2d, off2d, tot, NB);
    base_scan_k<<<1, 512, 0, stream>>>(tot, base, rp, NB, M, E);
    place_k<<<NBLK, 256, 0, stream>>>(src, dst, off2d, base, staging, E, NB);
    bucket_sort_k<<<NB, 256, 0, stream>>>(staging, base, rp, col, M);

    const int nblk = (M + 127) / 128;
    const int ablk = (M + 3) / 4;

    // layer 1 (gather from fp8 xb8; self path bf16 xb)
    aggregate1_k<<<ablk, 256, 0, stream>>>(xb8, col, rp, mean1, M);
    gemm_mfma_k<D_IN, false><<<nblk, 256, 0, stream>>>(
        mean1, w1lb, xb, w1rb, b1, h1, h8, nullptr, nullptr, nullptr, M);

    // layer 2 + fused head (gather from fp8 h8; self path bf16 h1)
    aggregate2_k<<<ablk, 256, 0, stream>>>(h8, col, rp, mean2, M);
    gemm_mfma_k<D_H, true><<<nblk, 256, 0, stream>>>(
        mean2, w2lb, h1, w2rb, b2, nullptr, nullptr, hw, hb, out, M);
}

// Round 16
// 231.672 us; speedup vs baseline: 1.0990x; 1.0048x over previous
//
#include <hip/hip_runtime.h>
#include <hip/hip_bf16.h>
#include <hip/hip_fp8.h>

#define D_IN 128
#define D_H  256
#define NBLK 128            // edge-chunk blocks for hist/place (must match!)
#define BSH  7              // 128 nodes per bucket
#define BNODES 128
#define MAXCH 6400          // max edges per chunk block (E=800000/128=6250)

typedef __attribute__((ext_vector_type(8))) short short8;   // 8 bf16 (4 VGPRs)
typedef __attribute__((ext_vector_type(4))) float floatx4;  // MFMA C/D frag

__device__ __forceinline__ unsigned short f2bf(float f) {
    __hip_bfloat16 h = __float2bfloat16(f);
    return *reinterpret_cast<unsigned short*>(&h);
}
__device__ __forceinline__ float bf2f(unsigned short s) {
    union { unsigned int u; float f; } v;
    v.u = ((unsigned int)s) << 16;
    return v.f;
}
__device__ __forceinline__ unsigned char f2fp8(float f) {
    __hip_fp8_e4m3 t(f);
    return (unsigned char)t.__x;
}

// exclusive scan of vals[0..NB) in place (NB<=512, 256 threads), part[256] scratch
__device__ __forceinline__ void excl_scan512(int* vals, int NB, int* part) {
    const int t = threadIdx.x;
    const int i0 = t * 2, i1 = t * 2 + 1;
    int v0 = (i0 < NB) ? vals[i0] : 0;
    int v1 = (i1 < NB) ? vals[i1] : 0;
    part[t] = v0 + v1;
    __syncthreads();
    for (int off = 1; off < 256; off <<= 1) {
        int u = (t >= off) ? part[t - off] : 0;
        __syncthreads();
        part[t] += u;
        __syncthreads();
    }
    const int pre = (t == 0) ? 0 : part[t - 1];
    if (i0 < NB) vals[i0] = pre;
    if (i1 < NB) vals[i1] = pre + v0;
    __syncthreads();
}

// ---- P1: LDS bucket histogram (blocks < NBLK, blocked chunks) + casts -----
__global__ void p1_hist_conv_k(const int* __restrict__ dst, int* __restrict__ cnt2d,
                               int E, int NB,
                               const float* __restrict__ x, unsigned short* __restrict__ xb,
                               unsigned char* __restrict__ xb8, int nx4,
                               const float* __restrict__ w1l, unsigned short* __restrict__ w1lb,
                               const float* __restrict__ w1r, unsigned short* __restrict__ w1rb, int nw14,
                               const float* __restrict__ w2l, unsigned short* __restrict__ w2lb,
                               const float* __restrict__ w2r, unsigned short* __restrict__ w2rb, int nw24) {
    if (blockIdx.x < NBLK) {
        __shared__ int h[512];                  // NB <= 512
        for (int i = threadIdx.x; i < NB; i += 256) h[i] = 0;
        __syncthreads();
        const int CH = (E + NBLK - 1) / NBLK;
        const int e0 = blockIdx.x * CH;
        const int e1 = min(e0 + CH, E);
        for (int e = e0 + threadIdx.x; e < e1; e += 256)
            atomicAdd(&h[dst[e] >> BSH], 1);    // LDS atomic (fast)
        __syncthreads();
        for (int i = threadIdx.x; i < NB; i += 256)
            cnt2d[blockIdx.x * NB + i] = h[i];
        return;
    }
    int i = (blockIdx.x - NBLK) * 256 + threadIdx.x;
    if (i < nx4) {
        float4 v = ((const float4*)x)[i];
        ushort4 u;
        u.x = f2bf(v.x); u.y = f2bf(v.y); u.z = f2bf(v.z); u.w = f2bf(v.w);
        ((ushort4*)xb)[i] = u;
        uchar4 c;
        c.x = f2fp8(v.x); c.y = f2fp8(v.y); c.z = f2fp8(v.z); c.w = f2fp8(v.w);
        ((uchar4*)xb8)[i] = c;
        return;
    }
    i -= nx4;
    const float* s; unsigned short* d; int k;
    if (i < nw14) { s = w1l; d = w1lb; k = i; }
    else {
        i -= nw14;
        if (i < nw14) { s = w1r; d = w1rb; k = i; }
        else {
            i -= nw14;
            if (i < nw24) { s = w2l; d = w2lb; k = i; }
            else {
                i -= nw24;
                if (i >= nw24) return;
                s = w2r; d = w2rb; k = i;
            }
        }
    }
    float4 v = ((const float4*)s)[k];
    ushort4 u;
    u.x = f2bf(v.x); u.y = f2bf(v.y); u.z = f2bf(v.z); u.w = f2bf(v.w);
    ((ushort4*)d)[k] = u;
}

// ---- S1: per-bucket scan over the NBLK block counts -----------------------
__global__ __launch_bounds__(NBLK) void bucket_scan_k(const int* __restrict__ cnt2d,
                                                      int* __restrict__ off2d,
                                                      int* __restrict__ tot, int NB) {
    const int B = blockIdx.x, t = threadIdx.x;
    __shared__ int sc[NBLK];
    __shared__ int orig[NBLK];
    int v = cnt2d[t * NB + B];
    orig[t] = v; sc[t] = v;
    __syncthreads();
    for (int off = 1; off < NBLK; off <<= 1) {
        int u = (t >= off) ? sc[t - off] : 0;
        __syncthreads();
        sc[t] += u;
        __syncthreads();
    }
    off2d[t * NB + B] = sc[t] - orig[t];
    if (t == NBLK - 1) tot[B] = sc[t];
}

// ---- P2: two-level multi-split: LDS counting sort, coalesced copy-out -----
// pack = dst<<16 | src (both < 65536). Bucket bases derived in-block from tot.
__global__ __launch_bounds__(256) void place_k(const int* __restrict__ src,
                                               const int* __restrict__ dst,
                                               const int* __restrict__ off2d,
                                               const int* __restrict__ tot,
                                               unsigned int* __restrict__ staging,
                                               int E, int NB) {
    __shared__ unsigned int lstage[MAXCH];
    __shared__ int lstart[512], lcur[512], runstart[512];
    __shared__ int part[256];
    const int b = blockIdx.x, tid = threadIdx.x;
    const int CH = (E + NBLK - 1) / NBLK;
    const int e0 = b * CH;
    const int e1 = min(e0 + CH, E);
    const int n = e1 - e0;

    for (int i = tid; i < NB; i += 256) { lstart[i] = 0; runstart[i] = tot[i]; }
    __syncthreads();
    for (int e = e0 + tid; e < e1; e += 256)
        atomicAdd(&lstart[dst[e] >> BSH], 1);
    __syncthreads();
    excl_scan512(lstart, NB, part);             // lstart = local excl prefix
    excl_scan512(runstart, NB, part);           // runstart = global bucket base
    for (int i = tid; i < NB; i += 256) {
        runstart[i] += off2d[b * NB + i];       // + this block's offset in bucket
        lcur[i] = lstart[i];
    }
    __syncthreads();
    for (int e = e0 + tid; e < e1; e += 256) {
        const int d = dst[e];
        const int pos = atomicAdd(&lcur[d >> BSH], 1);
        lstage[pos] = ((unsigned int)d << 16) | (unsigned int)src[e];
    }
    __syncthreads();
    for (int i = tid; i < n; i += 256) {
        const unsigned int u = lstage[i];
        const int bkt = (int)(u >> (16 + BSH));
        staging[runstart[bkt] + (i - lstart[bkt])] = u;
    }
}

// ---- P3: per-bucket counting sort -> rp + col -----------------------------
__global__ __launch_bounds__(256) void bucket_sort_k(const unsigned int* __restrict__ staging,
                                                     const int* __restrict__ tot,
                                                     int* __restrict__ rp, int* __restrict__ col,
                                                     int M, int NB) {
    const int B = blockIdx.x, tid = threadIdx.x;
    __shared__ int red[256];
    __shared__ int h[BNODES], sc[BNODES], cur[BNODES];
    __shared__ int s0s, s1s;
    int acc = 0;
    for (int i = tid; i < B; i += 256) acc += tot[i];
    red[tid] = acc; __syncthreads();
    for (int off = 128; off > 0; off >>= 1) {
        if (tid < off) red[tid] += red[tid + off];
        __syncthreads();
    }
    if (tid == 0) { s0s = red[0]; s1s = red[0] + tot[B]; }
    if (tid < BNODES) h[tid] = 0;
    __syncthreads();
    const int s0 = s0s, s1 = s1s;
    for (int i = s0 + tid; i < s1; i += 256)
        atomicAdd(&h[(staging[i] >> 16) & (BNODES - 1)], 1);
    __syncthreads();
    if (tid < BNODES) sc[tid] = h[tid];
    __syncthreads();
    for (int off = 1; off < BNODES; off <<= 1) {
        int v = 0;
        if (tid < BNODES && tid >= off) v = sc[tid - off];
        __syncthreads();
        if (tid < BNODES) sc[tid] += v;
        __syncthreads();
    }
    if (tid < BNODES) {
        const int excl = sc[tid] - h[tid];
        const int node = B * BNODES + tid;
        if (node < M) rp[node] = s0 + excl;
        cur[tid] = s0 + excl;
    }
    if (B == NB - 1 && tid == 0) rp[M] = s1;    // == E
    __syncthreads();
    for (int i = s0 + tid; i < s1; i += 256) {
        const unsigned int u = staging[i];
        const int pos = atomicAdd(&cur[(u >> 16) & (BNODES - 1)], 1);
        col[pos] = (int)(u & 0xFFFFu);
    }
}

// ------------- agg layer 1: fp8 d=128, half-wave pair gather ---------------
template <int UNP>
__device__ __forceinline__ int agg1_stage(const unsigned char* __restrict__ X8,
                                          const int* __restrict__ col,
                                          int j, int e, int sel, int l32, float* acc) {
    for (; j + 2 * UNP <= e; j += 2 * UNP) {
        int c0[UNP], c1[UNP];
#pragma unroll
        for (int u = 0; u < UNP; ++u) { c0[u] = col[j + 2 * u]; c1[u] = col[j + 2 * u + 1]; }
        unsigned int vals[UNP];
#pragma unroll
        for (int u = 0; u < UNP; ++u) {
            const int cs = sel ? c1[u] : c0[u];
            vals[u] = *(const unsigned int*)(X8 + (size_t)cs * 128 + l32 * 4);
        }
#pragma unroll
        for (int u = 0; u < UNP; ++u) {
            __hip_fp8x4_e4m3 p;
            p.__x = vals[u];
            float4 f = (float4)p;
            acc[0] += f.x; acc[1] += f.y; acc[2] += f.z; acc[3] += f.w;
        }
    }
    return j;
}

__global__ __launch_bounds__(256) void aggregate1_k(
    const unsigned char* __restrict__ X8, const int* __restrict__ col,
    const int* __restrict__ rp, unsigned short* __restrict__ out, int Mnodes) {
    int node = __builtin_amdgcn_readfirstlane((blockIdx.x << 2) + (threadIdx.x >> 6));
    if (node >= Mnodes) return;
    const int lane = threadIdx.x & 63;
    const int sel = lane >> 5;
    const int l32 = lane & 31;
    const int s = rp[node], e = rp[node + 1];
    float acc[4] = {0.f, 0.f, 0.f, 0.f};

    int j = s;
    j = agg1_stage<4>(X8, col, j, e, sel, l32, acc);
    j = agg1_stage<2>(X8, col, j, e, sel, l32, acc);
    j = agg1_stage<1>(X8, col, j, e, sel, l32, acc);
    if (j < e) {
        const int c0 = col[j];
        if (sel == 0) {
            unsigned int v = *(const unsigned int*)(X8 + (size_t)c0 * 128 + l32 * 4);
            __hip_fp8x4_e4m3 p;
            p.__x = v;
            float4 f = (float4)p;
            acc[0] += f.x; acc[1] += f.y; acc[2] += f.z; acc[3] += f.w;
        }
    }
#pragma unroll
    for (int k = 0; k < 4; ++k) acc[k] += __shfl_xor(acc[k], 32, 64);
    const float inv = 1.f / fmaxf((float)(e - s), 1.f);
    if (sel == 0) {
        ushort4 o;
        o.x = f2bf(acc[0] * inv); o.y = f2bf(acc[1] * inv);
        o.z = f2bf(acc[2] * inv); o.w = f2bf(acc[3] * inv);
        *(ushort4*)(out + (size_t)node * 128 + l32 * 4) = o;
    }
}

// ------------- agg layer 2: fp8 d=256, full-wave ---------------------------
template <int UN>
__device__ __forceinline__ int agg_stage_fp8(const unsigned char* __restrict__ X8,
                                             const int* __restrict__ col,
                                             int j, int e, int lane, float* acc) {
    for (; j + UN <= e; j += UN) {
        int cs[UN];
#pragma unroll
        for (int u = 0; u < UN; ++u) cs[u] = col[j + u];
        unsigned int vals[UN];
#pragma unroll
        for (int u = 0; u < UN; ++u)
            vals[u] = *(const unsigned int*)(X8 + (size_t)cs[u] * 256 + lane * 4);
#pragma unroll
        for (int u = 0; u < UN; ++u) {
            __hip_fp8x4_e4m3 p;
            p.__x = vals[u];
            float4 f = (float4)p;
            acc[0] += f.x; acc[1] += f.y; acc[2] += f.z; acc[3] += f.w;
        }
    }
    return j;
}

__global__ __launch_bounds__(256) void aggregate2_k(
    const unsigned char* __restrict__ X8, const int* __restrict__ col,
    const int* __restrict__ rp, unsigned short* __restrict__ out, int Mnodes) {
    int node = __builtin_amdgcn_readfirstlane((blockIdx.x << 2) + (threadIdx.x >> 6));
    if (node >= Mnodes) return;
    const int lane = threadIdx.x & 63;
    const int s = rp[node], e = rp[node + 1];
    float acc[4] = {0.f, 0.f, 0.f, 0.f};

    int j = s;
    j = agg_stage_fp8<8>(X8, col, j, e, lane, acc);
    j = agg_stage_fp8<4>(X8, col, j, e, lane, acc);
    j = agg_stage_fp8<2>(X8, col, j, e, lane, acc);
    j = agg_stage_fp8<1>(X8, col, j, e, lane, acc);

    const float inv = 1.f / fmaxf((float)(e - s), 1.f);
    ushort4 o;
    o.x = f2bf(acc[0] * inv); o.y = f2bf(acc[1] * inv);
    o.z = f2bf(acc[2] * inv); o.w = f2bf(acc[3] * inv);
    *(ushort4*)(out + (size_t)node * 256 + lane * 4) = o;
}

// ---------------- dual-input bf16 MFMA GEMM, 128x256, reg double-buffer ----
template <int K, bool HEAD>
__global__ __launch_bounds__(256, 2) void gemm_mfma_k(
    const unsigned short* __restrict__ A1, const unsigned short* __restrict__ W1,
    const unsigned short* __restrict__ A2, const unsigned short* __restrict__ W2,
    const float* __restrict__ bias, unsigned short* __restrict__ Hout,
    unsigned char* __restrict__ Hout8,
    const float* __restrict__ hw, const float* __restrict__ hb,
    float* __restrict__ out, int M) {
    __shared__ __align__(16) unsigned short sA[128 * 40];
    __shared__ __align__(16) unsigned short sB[256 * 40];
    __shared__ float head_acc[128];

    constexpr int NCK = K / 32;
    constexpr int NC = 2 * NCK;

    const int tid = threadIdx.x;
    const int wave = tid >> 6;
    const int lane = tid & 63;
    const int c = lane & 15;
    const int q = lane >> 4;
    const int m0 = blockIdx.x * 128;

    if (HEAD && tid < 128) head_acc[tid] = 0.f;

    floatx4 acc[8][4];
#pragma unroll
    for (int mi = 0; mi < 8; ++mi)
#pragma unroll
        for (int ni = 0; ni < 4; ++ni) acc[mi][ni] = (floatx4){0.f, 0.f, 0.f, 0.f};

    const int arow = tid >> 1;
    const int aseg = (tid & 1) * 16;
    const int brow = tid >> 2;
    const int bseg = (tid & 3) * 8;
    int gr = m0 + arow;
    if (gr >= M) gr = M - 1;

    auto loadChunk = [&](int t, short8& a0, short8& a1, short8* b) {
        const unsigned short* Ap = (t >= NCK) ? A2 : A1;
        const unsigned short* Wp = (t >= NCK) ? W2 : W1;
        const int k0 = (t & (NCK - 1)) * 32;
        a0 = *(const short8*)(Ap + (size_t)gr * K + k0 + aseg);
        a1 = *(const short8*)(Ap + (size_t)gr * K + k0 + aseg + 8);
#pragma unroll
        for (int i = 0; i < 4; ++i)
            b[i] = *(const short8*)(Wp + (size_t)(brow + i * 64) * K + k0 + bseg);
    };

    short8 ca0, ca1, cb[4], na0, na1, nb[4];
    loadChunk(0, ca0, ca1, cb);

#pragma unroll 1
    for (int t = 0; t < NC; ++t) {
        __syncthreads();
        *(short8*)&sA[arow * 40 + aseg] = ca0;
        *(short8*)&sA[arow * 40 + aseg + 8] = ca1;
#pragma unroll
        for (int i = 0; i < 4; ++i)
            *(short8*)&sB[(brow + i * 64) * 40 + bseg] = cb[i];
        if (t + 1 < NC)
            loadChunk(t + 1, na0, na1, nb);
        __syncthreads();

        short8 af[8], bf[4];
#pragma unroll
        for (int mi = 0; mi < 8; ++mi)
            af[mi] = *(const short8*)&sA[(mi * 16 + c) * 40 + q * 8];
#pragma unroll
        for (int ni = 0; ni < 4; ++ni)
            bf[ni] = *(const short8*)&sB[(wave * 64 + ni * 16 + c) * 40 + q * 8];
#pragma unroll
        for (int mi = 0; mi < 8; ++mi)
#pragma unroll
            for (int ni = 0; ni < 4; ++ni)
                acc[mi][ni] = __builtin_amdgcn_mfma_f32_16x16x32_bf16(
                    af[mi], bf[ni], acc[mi][ni], 0, 0, 0);

        ca0 = na0; ca1 = na1;
#pragma unroll
        for (int i = 0; i < 4; ++i) cb[i] = nb[i];
    }

    if (!HEAD) {
#pragma unroll
        for (int mi = 0; mi < 8; ++mi)
#pragma unroll
            for (int ni = 0; ni < 4; ++ni) {
                const int n = wave * 64 + ni * 16 + c;
                const float bv = bias[n];
#pragma unroll
                for (int reg = 0; reg < 4; ++reg) {
                    const int m = m0 + mi * 16 + q * 4 + reg;
                    if (m < M) {
                        float v = fmaxf(acc[mi][ni][reg] + bv, 0.f);
                        Hout[(size_t)m * 256 + n] = f2bf(v);
                        Hout8[(size_t)m * 256 + n] = f2fp8(v);
                    }
                }
            }
    } else {
#pragma unroll
        for (int mi = 0; mi < 8; ++mi) {
            float p[4] = {0.f, 0.f, 0.f, 0.f};
#pragma unroll
            for (int ni = 0; ni < 4; ++ni) {
                const int n = wave * 64 + ni * 16 + c;
                const float bv = bias[n];
                const float hv = hw[n];
#pragma unroll
                for (int reg = 0; reg < 4; ++reg)
                    p[reg] += fmaxf(acc[mi][ni][reg] + bv, 0.f) * hv;
            }
#pragma unroll
            for (int reg = 0; reg < 4; ++reg) {
                float v = p[reg];
                v += __shfl_xor(v, 1, 64);
                v += __shfl_xor(v, 2, 64);
                v += __shfl_xor(v, 4, 64);
                v += __shfl_xor(v, 8, 64);
                if (c == 0) atomicAdd(&head_acc[mi * 16 + q * 4 + reg], v);
            }
        }
        __syncthreads();
        if (tid < 128) {
            const int m = m0 + tid;
            if (m < M) out[m] = head_acc[tid] + hb[0];
        }
    }
}

// ---------------- launch ----------------
extern "C" void kernel_launch(void* const* d_in, const int* in_sizes, int n_in,
                              void* d_out, int out_size, void* d_ws, size_t ws_size,
                              hipStream_t stream) {
    const float* x    = (const float*)d_in[0];
    const int*   ei   = (const int*)d_in[1];
    const float* W1l  = (const float*)d_in[2];
    const float* b1   = (const float*)d_in[3];
    const float* W1r  = (const float*)d_in[4];
    const float* W2l  = (const float*)d_in[5];
    const float* b2   = (const float*)d_in[6];
    const float* W2r  = (const float*)d_in[7];
    const float* hw   = (const float*)d_in[8];
    const float* hb   = (const float*)d_in[9];
    float* out = (float*)d_out;

    const int M = in_sizes[0] / D_IN;       // 50000 (< 65536: packs in 16b)
    const int E = in_sizes[1] / 2;          // 800000 (chunk 6250 <= MAXCH)
    const int* src = ei;
    const int* dst = ei + E;
    const int NB = (M + BNODES - 1) / BNODES;   // 391 buckets

    size_t off = 0;
    auto alloc = [&](size_t bytes) -> void* {
        void* p = (char*)d_ws + off;
        off += (bytes + 255) & ~(size_t)255;
        return p;
    };
    int* cnt2d = (int*)alloc((size_t)NBLK * NB * 4);
    int* off2d = (int*)alloc((size_t)NBLK * NB * 4);
    int* tot   = (int*)alloc((size_t)NB * 4);
    unsigned int* staging = (unsigned int*)alloc((size_t)E * 4);
    int* rp    = (int*)alloc((size_t)(M + 1) * 4);
    int* col   = (int*)alloc((size_t)E * 4);
    unsigned short* xb    = (unsigned short*)alloc((size_t)M * D_IN * 2);
    unsigned char*  xb8   = (unsigned char*)alloc((size_t)M * D_IN);
    unsigned short* w1lb  = (unsigned short*)alloc((size_t)D_H * D_IN * 2);
    unsigned short* w1rb  = (unsigned short*)alloc((size_t)D_H * D_IN * 2);
    unsigned short* w2lb  = (unsigned short*)alloc((size_t)D_H * D_H * 2);
    unsigned short* w2rb  = (unsigned short*)alloc((size_t)D_H * D_H * 2);
    unsigned short* mean1 = (unsigned short*)alloc((size_t)M * D_IN * 2);
    unsigned short* h1    = (unsigned short*)alloc((size_t)M * D_H * 2);
    unsigned char*  h8    = (unsigned char*)alloc((size_t)M * D_H);
    unsigned short* mean2 = (unsigned short*)alloc((size_t)M * D_H * 2);

    // CSR build (no device-scope atomics) + conversions
    const int nx4 = (M * D_IN) / 4;
    const int nw14 = (D_H * D_IN) / 4;
    const int nw24 = (D_H * D_H) / 4;
    const int tot4 = nx4 + 2 * nw14 + 2 * nw24;
    const int convblk = (tot4 + 255) / 256;
    p1_hist_conv_k<<<NBLK + convblk, 256, 0, stream>>>(
        dst, cnt2d, E, NB,
        x, xb, xb8, nx4, W1l, w1lb, W1r, w1rb, nw14, W2l, w2lb, W2r, w2rb, nw24);
    bucket_scan_k<<<NB, NBLK, 0, stream>>>(cnt2d, off2d, tot, NB);
    place_k<<<NBLK, 256, 0, stream>>>(src, dst, off2d, tot, staging, E, NB);
    bucket_sort_k<<<NB, 256, 0, stream>>>(staging, tot, rp, col, M, NB);

    const int nblk = (M + 127) / 128;
    const int ablk = (M + 3) / 4;

    // layer 1 (gather from fp8 xb8; self path bf16 xb)
    aggregate1_k<<<ablk, 256, 0, stream>>>(xb8, col, rp, mean1, M);
    gemm_mfma_k<D_IN, false><<<nblk, 256, 0, stream>>>(
        mean1, w1lb, xb, w1rb, b1, h1, h8, nullptr, nullptr, nullptr, M);

    // layer 2 + fused head (gather from fp8 h8; self path bf16 h1)
    aggregate2_k<<<ablk, 256, 0, stream>>>(h8, col, rp, mean2, M);
    gemm_mfma_k<D_H, true><<<nblk, 256, 0, stream>>>(
        mean2, w2lb, h1, w2rb, b2, nullptr, nullptr, hw, hb, out, M);
}